// Round 12
// baseline (433.043 us; speedup 1.0000x reference)
//
#include <hip/hip_runtime.h>
#include <cstdint>
#include <cstddef>

#define NEG_SLOPE 0.2f

typedef __attribute__((ext_vector_type(8))) short short8;
typedef __attribute__((ext_vector_type(4))) float f32x4;

__device__ __forceinline__ float lrelu(float v) { return v > 0.f ? v : NEG_SLOPE * v; }

__device__ __forceinline__ unsigned short f2bf(float x) {
    unsigned u = __float_as_uint(x);
    u = (u + 0x7FFFu + ((u >> 16) & 1u)) >> 16;
    return (unsigned short)u;
}
__device__ __forceinline__ float bf2f(unsigned short h) {
    return __uint_as_float(((unsigned)h) << 16);
}

// trunc split: hi = top 16 bits, lo = bf16_trunc(x - hi). Must stay identical
// everywhere it is used (k_mm CONV path and k_agg split-store).
__device__ __forceinline__ void splitbf(float v, unsigned short& hb, unsigned short& lb) {
    unsigned u = __float_as_uint(v);
    hb = (unsigned short)(u >> 16);
    float hf = __uint_as_float(u & 0xFFFF0000u);
    float lf = v - hf;
    lb = (unsigned short)(__float_as_uint(lf) >> 16);
}

// ---------------- CSR build ----------------
__global__ void k_count(const int* __restrict__ ei, int E, int* __restrict__ counts) {
    int i = blockIdx.x * blockDim.x + threadIdx.x;
    if (i < E) atomicAdd(&counts[ei[E + i]], 1);
}

__global__ __launch_bounds__(256) void k_scan_local(const int* __restrict__ counts,
        int* __restrict__ local_ex, int* __restrict__ bsums, int Nn) {
    int base = blockIdx.x * 1024;
    int tid = threadIdx.x;
    int idx = base + tid * 4;
    int4 v = make_int4(0, 0, 0, 0);
    if (idx + 3 < Nn) {
        v = *reinterpret_cast<const int4*>(&counts[idx]);
    } else {
        if (idx + 0 < Nn) v.x = counts[idx + 0];
        if (idx + 1 < Nn) v.y = counts[idx + 1];
        if (idx + 2 < Nn) v.z = counts[idx + 2];
        if (idx + 3 < Nn) v.w = counts[idx + 3];
    }
    int t = v.x + v.y + v.z + v.w;
    int lane = tid & 63, wave = tid >> 6;
    int s = t;
    #pragma unroll
    for (int off = 1; off < 64; off <<= 1) {
        int u = __shfl_up(s, off);
        if (lane >= off) s += u;
    }
    __shared__ int wsum[4];
    if (lane == 63) wsum[wave] = s;
    __syncthreads();
    int wo = 0;
    #pragma unroll
    for (int wv = 0; wv < 4; ++wv) wo += (wv < wave) ? wsum[wv] : 0;
    int ex = wo + s - t;
    int4 o;
    o.x = ex; o.y = ex + v.x; o.z = ex + v.x + v.y; o.w = ex + v.x + v.y + v.z;
    if (idx + 3 < Nn) {
        *reinterpret_cast<int4*>(&local_ex[idx]) = o;
    } else {
        if (idx + 0 < Nn) local_ex[idx + 0] = o.x;
        if (idx + 1 < Nn) local_ex[idx + 1] = o.y;
        if (idx + 2 < Nn) local_ex[idx + 2] = o.z;
        if (idx + 3 < Nn) local_ex[idx + 3] = o.w;
    }
    if (tid == 255) bsums[blockIdx.x] = wo + s;
}

__global__ __launch_bounds__(256) void k_scan_add(const int* __restrict__ local_ex,
        const int* __restrict__ bsums, int* __restrict__ indptr, int* __restrict__ cursor,
        int Nn, int Etot, int NB) {
    __shared__ int pref[64];
    int tid = threadIdx.x;
    if (tid < 64) {
        int v = (tid < NB) ? bsums[tid] : 0;
        int s = v;
        #pragma unroll
        for (int off = 1; off < 64; off <<= 1) {
            int u = __shfl_up(s, off);
            if ((tid & 63) >= off) s += u;
        }
        pref[tid] = s - v;   // exclusive prefix
    }
    __syncthreads();
    int i = blockIdx.x * 256 + tid;
    if (i < Nn) {
        int val = local_ex[i] + pref[i >> 10];
        indptr[i] = val;
        cursor[i] = val;
    } else if (i == Nn) {
        indptr[Nn] = Etot;
    }
}

__global__ void k_scatter(const int* __restrict__ ei, int E, int* __restrict__ cursor,
                          int* __restrict__ csr_src) {
    int i = blockIdx.x * blockDim.x + threadIdx.x;
    if (i < E) {
        int s = ei[i], d = ei[E + i];
        int pos = atomicAdd(&cursor[d], 1);
        csr_src[pos] = s;
    }
}

// ---------------- pack B ----------------
__device__ __forceinline__ void packB_one(const float* __restrict__ W,
        unsigned short* __restrict__ Ph, unsigned short* __restrict__ Pl,
        int K, int M, int tid) {
    int KS8 = K >> 3;
    int col = tid / KS8;
    int k = (tid - col * KS8) << 3;
    short8 hv, lv;
    #pragma unroll
    for (int j = 0; j < 8; ++j) {
        float x = W[(size_t)(k + j) * M + col];
        unsigned short hb = f2bf(x);
        hv[j] = (short)hb;
        lv[j] = (short)f2bf(x - bf2f(hb));
    }
    int ct64 = col >> 6, c = col & 63;
    int fb = c >> 4, cl = c & 15;
    int ks = k >> 5, kg = (k >> 3) & 3;
    int lane = cl | (kg << 4);
    size_t off = (((size_t)ct64 * (K >> 5) + ks) * 4 + fb) * 64 + lane;
    *reinterpret_cast<short8*>(Ph + off * 8) = hv;
    *reinterpret_cast<short8*>(Pl + off * 8) = lv;
}

__global__ __launch_bounds__(256) void k_packB3(const float* __restrict__ W1,
        const float* __restrict__ W2, const float* __restrict__ W3,
        unsigned short* p1h, unsigned short* p1l,
        unsigned short* p2h, unsigned short* p2l,
        unsigned short* p3h, unsigned short* p3l) {
    int tid = blockIdx.x * 256 + threadIdx.x;
    if (tid < 4096)        packB_one(W1, p1h, p1l, 128, 256, tid);
    else if (tid < 12288)  packB_one(W2, p2h, p2l, 256, 256, tid - 4096);
    else if (tid < 14336)  packB_one(W3, p3h, p3l, 256, 64, tid - 12288);
}

// ---------------- split-bf16 MFMA GEMM ----------------
template<int AF, int WR, int WC, bool CONV, int K>
__global__ __launch_bounds__(256) void k_mm(const float* __restrict__ A,
        const unsigned short* __restrict__ Aph, const unsigned short* __restrict__ Apl,
        const unsigned short* __restrict__ Bh, const unsigned short* __restrict__ Bl,
        unsigned short* __restrict__ C, const float* __restrict__ a_src, const float* __restrict__ a_dst,
        float* __restrict__ al_s, float* __restrict__ al_d, int Nrows, int M) {
    constexpr int BF = 4;
    constexpr int BR = WR * AF * 16;
    constexpr int KS = K >> 5;
    int wave = threadIdx.x >> 6, lane = threadIdx.x & 63;
    int wr = wave / WC, wc = wave % WC;
    int rt = blockIdx.x;
    int ct64 = blockIdx.y * WC + wc;
    int rl = lane & 15, kg = lane >> 4;
    const short8* B8h = reinterpret_cast<const short8*>(Bh);
    const short8* B8l = reinterpret_cast<const short8*>(Bl);

    const float* aptr[AF];
    const unsigned short *ahp[AF], *alp[AF];
    #pragma unroll
    for (int f = 0; f < AF; ++f) {
        int row = rt * BR + wr * (AF * 16) + f * 16 + rl;
        if (row > Nrows - 1) row = Nrows - 1;
        if constexpr (CONV) {
            aptr[f] = A + (size_t)row * K + kg * 8;
        } else {
            ahp[f] = Aph + (size_t)row * K + kg * 8;
            alp[f] = Apl + (size_t)row * K + kg * 8;
        }
    }

    f32x4 acc[AF][BF];
    #pragma unroll
    for (int i = 0; i < AF; ++i)
        #pragma unroll
        for (int j = 0; j < BF; ++j)
            acc[i][j] = (f32x4){0.f, 0.f, 0.f, 0.f};

    #pragma unroll
    for (int ks = 0; ks < KS; ++ks) {
        short8 a_h[AF], a_l[AF], b_h[BF], b_l[BF];
        #pragma unroll
        for (int f = 0; f < AF; ++f) {
            if constexpr (CONV) {
                const float* ap = aptr[f] + ks * 32;
                float4 v0 = *reinterpret_cast<const float4*>(ap);
                float4 v1 = *reinterpret_cast<const float4*>(ap + 4);
                float vv[8] = {v0.x, v0.y, v0.z, v0.w, v1.x, v1.y, v1.z, v1.w};
                #pragma unroll
                for (int j = 0; j < 8; ++j) {
                    unsigned short hb, lb;
                    splitbf(vv[j], hb, lb);
                    a_h[f][j] = (short)hb;
                    a_l[f][j] = (short)lb;
                }
            } else {
                a_h[f] = *reinterpret_cast<const short8*>(ahp[f] + ks * 32);
                a_l[f] = *reinterpret_cast<const short8*>(alp[f] + ks * 32);
            }
        }
        #pragma unroll
        for (int f = 0; f < BF; ++f) {
            size_t off = (((size_t)ct64 * KS + ks) * 4 + f) * 64 + lane;
            b_h[f] = B8h[off]; b_l[f] = B8l[off];
        }
        #pragma unroll
        for (int i = 0; i < AF; ++i)
            #pragma unroll
            for (int j = 0; j < BF; ++j) {
                acc[i][j] = __builtin_amdgcn_mfma_f32_16x16x32_bf16(a_l[i], b_h[j], acc[i][j], 0, 0, 0);
                acc[i][j] = __builtin_amdgcn_mfma_f32_16x16x32_bf16(a_h[i], b_l[j], acc[i][j], 0, 0, 0);
                acc[i][j] = __builtin_amdgcn_mfma_f32_16x16x32_bf16(a_h[i], b_h[j], acc[i][j], 0, 0, 0);
            }
    }

    int H = M >> 6;
    int head = ct64;
    int col0 = ct64 * 64;
    int cl = lane & 15, rgrp = lane >> 4;

    float as_[BF], ad_[BF];
    #pragma unroll
    for (int j = 0; j < BF; ++j) {
        as_[j] = a_src[col0 + j * 16 + cl];
        ad_[j] = a_dst[col0 + j * 16 + cl];
    }

    #pragma unroll
    for (int i = 0; i < AF; ++i) {
        int rowb = rt * BR + wr * (AF * 16) + i * 16 + rgrp * 4;
        #pragma unroll
        for (int r = 0; r < 4; ++r) {
            float sv = acc[i][0][r] * as_[0] + acc[i][1][r] * as_[1]
                     + acc[i][2][r] * as_[2] + acc[i][3][r] * as_[3];
            float dv = acc[i][0][r] * ad_[0] + acc[i][1][r] * ad_[1]
                     + acc[i][2][r] * ad_[2] + acc[i][3][r] * ad_[3];
            #pragma unroll
            for (int o = 1; o < 16; o <<= 1) {
                sv += __shfl_xor(sv, o);
                dv += __shfl_xor(dv, o);
            }
            int row = rowb + r;
            if (row < Nrows) {
                unsigned short* cp = &C[(size_t)row * M + col0 + cl];
                cp[0]  = f2bf(acc[i][0][r]);
                cp[16] = f2bf(acc[i][1][r]);
                cp[32] = f2bf(acc[i][2][r]);
                cp[48] = f2bf(acc[i][3][r]);
                if (cl == 0) {
                    al_s[(size_t)row * H + head] = sv;
                    al_d[(size_t)row * H + head] = dv;
                }
            }
        }
    }
}

// ---------------- fused softmax + aggregate (wave per destination node, H=4) ----------------
// Group softmax (per-head lane groups), invden hoisted, simple 8-unrolled gather (R9 form).
template <int H, bool ACT, bool POOL>    // TOT = H*64
__global__ __launch_bounds__(256) void k_agg(const unsigned short* __restrict__ hlin,
                      const float* __restrict__ al_s,
                      const float* __restrict__ al_d, const int* __restrict__ indptr,
                      const int* __restrict__ csr_src, const float* __restrict__ bias,
                      unsigned short* __restrict__ out_hi, unsigned short* __restrict__ out_lo,
                      float* __restrict__ outf, const int* __restrict__ batch,
                      int* __restrict__ gcnt, int Nn) {
    constexpr int TOT = H * 64;
    constexpr int VEC = TOT / 64;
    constexpr int CAP = 128;
    constexpr int GRPW = 64 / H;   // lanes per head group
    __shared__ float sp[4][CAP * H];
    __shared__ int   si[4][CAP];
    int w = threadIdx.x >> 6;
    int lane = threadIdx.x & 63;
    int node = (blockIdx.x * blockDim.x + threadIdx.x) >> 6;
    if (node >= Nn) return;
    int d = node;
    int p0 = indptr[d], p1 = indptr[d + 1];
    int deg = p1 - p0;
    int head = (lane * VEC) >> 6;       // == lane / GRPW

    float ad[H], e_self[H];
    if constexpr (H == 4) {
        float4 adv = *reinterpret_cast<const float4*>(&al_d[(size_t)d * 4]);
        float4 asv = *reinterpret_cast<const float4*>(&al_s[(size_t)d * 4]);
        ad[0] = adv.x; ad[1] = adv.y; ad[2] = adv.z; ad[3] = adv.w;
        e_self[0] = lrelu(asv.x + ad[0]); e_self[1] = lrelu(asv.y + ad[1]);
        e_self[2] = lrelu(asv.z + ad[2]); e_self[3] = lrelu(asv.w + ad[3]);
    } else {
        ad[0] = al_d[d];
        e_self[0] = lrelu(al_s[d] + ad[0]);
    }

    if (deg <= CAP) {
        int nb = (deg + 63) >> 6;
        // phase A: compute e per lane-edge (all heads), stash in LDS
        for (int b = 0; b < nb; ++b) {
            int l = b * 64 + lane;
            float e_h[H];
            if (l < deg) {
                int s = csr_src[p0 + l];
                si[w][l] = s;
                if constexpr (H == 4) {
                    float4 sv = *reinterpret_cast<const float4*>(&al_s[(size_t)s * 4]);
                    e_h[0] = lrelu(sv.x + ad[0]); e_h[1] = lrelu(sv.y + ad[1]);
                    e_h[2] = lrelu(sv.z + ad[2]); e_h[3] = lrelu(sv.w + ad[3]);
                } else {
                    e_h[0] = lrelu(al_s[s] + ad[0]);
                }
            } else {
                #pragma unroll
                for (int h = 0; h < H; ++h) e_h[h] = -1e30f;
            }
            #pragma unroll
            for (int h = 0; h < H; ++h) sp[w][l * H + h] = e_h[h];
        }
        // per-head group reduction: max
        int li = lane & (GRPW - 1);
        int tot = nb * 64;
        float mg = e_self[head];
        for (int l = li; l < tot; l += GRPW)
            mg = fmaxf(mg, sp[w][l * H + head]);
        #pragma unroll
        for (int o = 1; o < GRPW; o <<= 1)
            mg = fmaxf(mg, __shfl_xor(mg, o));
        // exp + denom (own head only), pv written back raw
        float deng = 0.f;
        for (int l = li; l < tot; l += GRPW) {
            float pv = __expf(sp[w][l * H + head] - mg);
            sp[w][l * H + head] = pv;
            deng += pv;
        }
        #pragma unroll
        for (int o = 1; o < GRPW; o <<= 1)
            deng += __shfl_xor(deng, o);
        float esx = __expf(e_self[head] - mg);
        deng += esx;
        float invden = 1.f / deng;

        // gather with raw weights; invden applied once at end
        float4 accv = make_float4(0.f, 0.f, 0.f, 0.f);
        {
            const unsigned short* hp = hlin + (size_t)d * TOT + lane * VEC;
            if constexpr (VEC == 4) {
                ushort4 hv = *reinterpret_cast<const ushort4*>(hp);
                accv.x = esx * bf2f(hv.x); accv.y = esx * bf2f(hv.y);
                accv.z = esx * bf2f(hv.z); accv.w = esx * bf2f(hv.w);
            } else {
                accv.x = esx * bf2f(hp[0]);
            }
        }
        int e = 0;
        for (; e + 8 <= deg; e += 8) {
            int s0 = si[w][e + 0], s1 = si[w][e + 1], s2 = si[w][e + 2], s3 = si[w][e + 3];
            int s4 = si[w][e + 4], s5 = si[w][e + 5], s6 = si[w][e + 6], s7 = si[w][e + 7];
            float a0 = sp[w][(e + 0) * H + head];
            float a1 = sp[w][(e + 1) * H + head];
            float a2 = sp[w][(e + 2) * H + head];
            float a3 = sp[w][(e + 3) * H + head];
            float a4 = sp[w][(e + 4) * H + head];
            float a5 = sp[w][(e + 5) * H + head];
            float a6 = sp[w][(e + 6) * H + head];
            float a7 = sp[w][(e + 7) * H + head];
            if constexpr (VEC == 4) {
                ushort4 r0 = *reinterpret_cast<const ushort4*>(hlin + (size_t)s0 * TOT + lane * 4);
                ushort4 r1 = *reinterpret_cast<const ushort4*>(hlin + (size_t)s1 * TOT + lane * 4);
                ushort4 r2 = *reinterpret_cast<const ushort4*>(hlin + (size_t)s2 * TOT + lane * 4);
                ushort4 r3 = *reinterpret_cast<const ushort4*>(hlin + (size_t)s3 * TOT + lane * 4);
                ushort4 r4 = *reinterpret_cast<const ushort4*>(hlin + (size_t)s4 * TOT + lane * 4);
                ushort4 r5 = *reinterpret_cast<const ushort4*>(hlin + (size_t)s5 * TOT + lane * 4);
                ushort4 r6 = *reinterpret_cast<const ushort4*>(hlin + (size_t)s6 * TOT + lane * 4);
                ushort4 r7 = *reinterpret_cast<const ushort4*>(hlin + (size_t)s7 * TOT + lane * 4);
                accv.x += a0*bf2f(r0.x) + a1*bf2f(r1.x) + a2*bf2f(r2.x) + a3*bf2f(r3.x)
                        + a4*bf2f(r4.x) + a5*bf2f(r5.x) + a6*bf2f(r6.x) + a7*bf2f(r7.x);
                accv.y += a0*bf2f(r0.y) + a1*bf2f(r1.y) + a2*bf2f(r2.y) + a3*bf2f(r3.y)
                        + a4*bf2f(r4.y) + a5*bf2f(r5.y) + a6*bf2f(r6.y) + a7*bf2f(r7.y);
                accv.z += a0*bf2f(r0.z) + a1*bf2f(r1.z) + a2*bf2f(r2.z) + a3*bf2f(r3.z)
                        + a4*bf2f(r4.z) + a5*bf2f(r5.z) + a6*bf2f(r6.z) + a7*bf2f(r7.z);
                accv.w += a0*bf2f(r0.w) + a1*bf2f(r1.w) + a2*bf2f(r2.w) + a3*bf2f(r3.w)
                        + a4*bf2f(r4.w) + a5*bf2f(r5.w) + a6*bf2f(r6.w) + a7*bf2f(r7.w);
            } else {
                float r0 = bf2f(hlin[(size_t)s0 * TOT + lane]);
                float r1 = bf2f(hlin[(size_t)s1 * TOT + lane]);
                float r2 = bf2f(hlin[(size_t)s2 * TOT + lane]);
                float r3 = bf2f(hlin[(size_t)s3 * TOT + lane]);
                float r4 = bf2f(hlin[(size_t)s4 * TOT + lane]);
                float r5 = bf2f(hlin[(size_t)s5 * TOT + lane]);
                float r6 = bf2f(hlin[(size_t)s6 * TOT + lane]);
                float r7 = bf2f(hlin[(size_t)s7 * TOT + lane]);
                accv.x += a0*r0 + a1*r1 + a2*r2 + a3*r3 + a4*r4 + a5*r5 + a6*r6 + a7*r7;
            }
        }
        for (; e + 4 <= deg; e += 4) {
            int s0 = si[w][e + 0], s1 = si[w][e + 1];
            int s2 = si[w][e + 2], s3 = si[w][e + 3];
            float a0 = sp[w][(e + 0) * H + head];
            float a1 = sp[w][(e + 1) * H + head];
            float a2 = sp[w][(e + 2) * H + head];
            float a3 = sp[w][(e + 3) * H + head];
            if constexpr (VEC == 4) {
                ushort4 r0 = *reinterpret_cast<const ushort4*>(hlin + (size_t)s0 * TOT + lane * 4);
                ushort4 r1 = *reinterpret_cast<const ushort4*>(hlin + (size_t)s1 * TOT + lane * 4);
                ushort4 r2 = *reinterpret_cast<const ushort4*>(hlin + (size_t)s2 * TOT + lane * 4);
                ushort4 r3 = *reinterpret_cast<const ushort4*>(hlin + (size_t)s3 * TOT + lane * 4);
                accv.x += a0*bf2f(r0.x) + a1*bf2f(r1.x) + a2*bf2f(r2.x) + a3*bf2f(r3.x);
                accv.y += a0*bf2f(r0.y) + a1*bf2f(r1.y) + a2*bf2f(r2.y) + a3*bf2f(r3.y);
                accv.z += a0*bf2f(r0.z) + a1*bf2f(r1.z) + a2*bf2f(r2.z) + a3*bf2f(r3.z);
                accv.w += a0*bf2f(r0.w) + a1*bf2f(r1.w) + a2*bf2f(r2.w) + a3*bf2f(r3.w);
            } else {
                float r0 = bf2f(hlin[(size_t)s0 * TOT + lane]);
                float r1 = bf2f(hlin[(size_t)s1 * TOT + lane]);
                float r2 = bf2f(hlin[(size_t)s2 * TOT + lane]);
                float r3 = bf2f(hlin[(size_t)s3 * TOT + lane]);
                accv.x += a0 * r0 + a1 * r1 + a2 * r2 + a3 * r3;
            }
        }
        for (; e < deg; ++e) {
            int s = si[w][e];
            float a = sp[w][e * H + head];
            if constexpr (VEC == 4) {
                ushort4 rv = *reinterpret_cast<const ushort4*>(hlin + (size_t)s * TOT + lane * 4);
                accv.x += a * bf2f(rv.x); accv.y += a * bf2f(rv.y);
                accv.z += a * bf2f(rv.z); accv.w += a * bf2f(rv.w);
            } else {
                accv.x += a * bf2f(hlin[(size_t)s * TOT + lane]);
            }
        }
        if constexpr (VEC == 4) {
            int c0 = lane * 4;
            accv.x = accv.x * invden + bias[c0 + 0];
            accv.y = accv.y * invden + bias[c0 + 1];
            accv.z = accv.z * invden + bias[c0 + 2];
            accv.w = accv.w * invden + bias[c0 + 3];
            if (ACT) {
                accv.x = accv.x > 0.f ? accv.x : expm1f(accv.x);
                accv.y = accv.y > 0.f ? accv.y : expm1f(accv.y);
                accv.z = accv.z > 0.f ? accv.z : expm1f(accv.z);
                accv.w = accv.w > 0.f ? accv.w : expm1f(accv.w);
            }
            ushort4 hv, lv;
            splitbf(accv.x, hv.x, lv.x);
            splitbf(accv.y, hv.y, lv.y);
            splitbf(accv.z, hv.z, lv.z);
            splitbf(accv.w, hv.w, lv.w);
            *reinterpret_cast<ushort4*>(&out_hi[(size_t)d * TOT + c0]) = hv;
            *reinterpret_cast<ushort4*>(&out_lo[(size_t)d * TOT + c0]) = lv;
        } else {
            float o = accv.x * invden + bias[lane];
            if (ACT) o = o > 0.f ? o : expm1f(o);
            if constexpr (POOL) {
                int g = batch[d];
                atomicAdd(&outf[(size_t)g * 64 + lane], o);
                if (lane == 0) atomicAdd(&gcnt[g], 1);
            } else {
                unsigned short hb, lb;
                splitbf(o, hb, lb);
                out_hi[(size_t)d * TOT + lane] = hb;
                out_lo[(size_t)d * TOT + lane] = lb;
            }
        }
        return;
    }

    // ---- fallback: deg > CAP, serial 3-pass (no LDS) ----
    {
        float adh = ad[head];
        float es = e_self[head];
        float m = es;
        for (int e = p0; e < p1; ++e) {
            int s = csr_src[e];
            m = fmaxf(m, lrelu(al_s[(size_t)s * H + head] + adh));
        }
        float den = __expf(es - m);
        for (int e = p0; e < p1; ++e) {
            int s = csr_src[e];
            den += __expf(lrelu(al_s[(size_t)s * H + head] + adh) - m);
        }
        den = 1.f / den;
        float accv[VEC] = {};
        {
            float alpha = __expf(es - m) * den;
            const unsigned short* hp = hlin + (size_t)d * TOT + lane * VEC;
            #pragma unroll
            for (int v = 0; v < VEC; ++v) accv[v] = alpha * bf2f(hp[v]);
        }
        for (int e = p0; e < p1; ++e) {
            int s = csr_src[e];
            float alpha = __expf(lrelu(al_s[(size_t)s * H + head] + adh) - m) * den;
            const unsigned short* hp = hlin + (size_t)s * TOT + lane * VEC;
            #pragma unroll
            for (int v = 0; v < VEC; ++v) accv[v] += alpha * bf2f(hp[v]);
        }
        #pragma unroll
        for (int v = 0; v < VEC; ++v) {
            int c = lane * VEC + v;
            float o = accv[v] + bias[c];
            if (ACT) o = o > 0.f ? o : expm1f(o);
            accv[v] = o;
        }
        if constexpr (POOL) {
            int g = batch[d];
            atomicAdd(&outf[(size_t)g * 64 + lane], accv[0]);
            if (lane == 0) atomicAdd(&gcnt[g], 1);
        } else {
            #pragma unroll
            for (int v = 0; v < VEC; ++v) {
                unsigned short hb, lb;
                splitbf(accv[v], hb, lb);
                out_hi[(size_t)d * TOT + lane * VEC + v] = hb;
                out_lo[(size_t)d * TOT + lane * VEC + v] = lb;
            }
        }
    }
}

// ---------------- H=1 softmax + aggregate + mean-pool (layer 3) ----------------
// Wave per node; softmax computed once by the whole wave; gather uses 4 lane-groups
// x 16 lanes x ushort4 -> one instruction covers 4 edges (512B), 8 edges in flight.
__global__ __launch_bounds__(256) void k_agg1(const unsigned short* __restrict__ hlin,
        const float* __restrict__ al_s, const float* __restrict__ al_d,
        const int* __restrict__ indptr, const int* __restrict__ csr_src,
        const float* __restrict__ bias, float* __restrict__ gsum,
        const int* __restrict__ batch, int* __restrict__ gcnt, int Nn) {
    constexpr int CAP = 128;
    __shared__ float sp[4][CAP];
    __shared__ int   si[4][CAP];
    int w = threadIdx.x >> 6;
    int lane = threadIdx.x & 63;
    int d = (blockIdx.x * blockDim.x + threadIdx.x) >> 6;
    if (d >= Nn) return;
    int p0 = indptr[d], p1 = indptr[d + 1];
    int deg = p1 - p0;
    float adq = al_d[d];
    float e_self = lrelu(al_s[d] + adq);
    int g = lane >> 4, li = lane & 15;

    if (deg <= CAP) {
        float m = e_self;
        for (int l = lane; l < deg; l += 64) {
            int s = csr_src[p0 + l];
            si[w][l] = s;
            float e = lrelu(al_s[s] + adq);
            sp[w][l] = e;
            m = fmaxf(m, e);
        }
        #pragma unroll
        for (int o = 1; o < 64; o <<= 1) m = fmaxf(m, __shfl_xor(m, o));
        float den = 0.f;
        for (int l = lane; l < deg; l += 64) {
            float pv = __expf(sp[w][l] - m);
            sp[w][l] = pv;
            den += pv;
        }
        #pragma unroll
        for (int o = 1; o < 64; o <<= 1) den += __shfl_xor(den, o);
        float esx = __expf(e_self - m);
        den += esx;
        float invden = 1.f / den;

        const unsigned short* base = hlin + li * 4;
        float4 acc = make_float4(0.f, 0.f, 0.f, 0.f);
        if (g == 0) {
            ushort4 hv = *reinterpret_cast<const ushort4*>(base + (size_t)d * 64);
            acc.x = esx * bf2f(hv.x); acc.y = esx * bf2f(hv.y);
            acc.z = esx * bf2f(hv.z); acc.w = esx * bf2f(hv.w);
        }
        for (int e = 0; e < deg; e += 8) {
            int e0 = e + g, e1 = e + 4 + g;
            bool v0 = e0 < deg, v1 = e1 < deg;
            int s0 = v0 ? si[w][e0] : d;
            int s1 = v1 ? si[w][e1] : d;
            float a0 = v0 ? sp[w][e0] : 0.f;
            float a1 = v1 ? sp[w][e1] : 0.f;
            ushort4 r0 = *reinterpret_cast<const ushort4*>(base + (size_t)s0 * 64);
            ushort4 r1 = *reinterpret_cast<const ushort4*>(base + (size_t)s1 * 64);
            acc.x += a0 * bf2f(r0.x) + a1 * bf2f(r1.x);
            acc.y += a0 * bf2f(r0.y) + a1 * bf2f(r1.y);
            acc.z += a0 * bf2f(r0.z) + a1 * bf2f(r1.z);
            acc.w += a0 * bf2f(r0.w) + a1 * bf2f(r1.w);
        }
        #pragma unroll
        for (int o = 16; o < 64; o <<= 1) {
            acc.x += __shfl_xor(acc.x, o);
            acc.y += __shfl_xor(acc.y, o);
            acc.z += __shfl_xor(acc.z, o);
            acc.w += __shfl_xor(acc.w, o);
        }
        if (g == 0) {
            int c0 = li * 4;
            acc.x = acc.x * invden + bias[c0 + 0];
            acc.y = acc.y * invden + bias[c0 + 1];
            acc.z = acc.z * invden + bias[c0 + 2];
            acc.w = acc.w * invden + bias[c0 + 3];
            int gg = batch[d];
            atomicAdd(&gsum[(size_t)gg * 64 + c0 + 0], acc.x);
            atomicAdd(&gsum[(size_t)gg * 64 + c0 + 1], acc.y);
            atomicAdd(&gsum[(size_t)gg * 64 + c0 + 2], acc.z);
            atomicAdd(&gsum[(size_t)gg * 64 + c0 + 3], acc.w);
            if (lane == 0) atomicAdd(&gcnt[gg], 1);
        }
        return;
    }
    // fallback deg > CAP: serial, 1 channel/lane
    {
        float m = e_self;
        for (int e = p0; e < p1; ++e)
            m = fmaxf(m, lrelu(al_s[csr_src[e]] + adq));
        float den = __expf(e_self - m);
        for (int e = p0; e < p1; ++e)
            den += __expf(lrelu(al_s[csr_src[e]] + adq) - m);
        float invden = 1.f / den;
        float acc = __expf(e_self - m) * bf2f(hlin[(size_t)d * 64 + lane]);
        for (int e = p0; e < p1; ++e) {
            int s = csr_src[e];
            float a = __expf(lrelu(al_s[s] + adq) - m);
            acc += a * bf2f(hlin[(size_t)s * 64 + lane]);
        }
        float o = acc * invden + bias[lane];
        int gg = batch[d];
        atomicAdd(&gsum[(size_t)gg * 64 + lane], o);
        if (lane == 0) atomicAdd(&gcnt[gg], 1);
    }
}

// ---------------- final linear ----------------
__global__ void k_final(const float* __restrict__ gsum, const int* __restrict__ gcnt,
                        const float* __restrict__ lin_w, const float* __restrict__ lin_b,
                        float* __restrict__ out, int Gn) {
    int g = (blockIdx.x * blockDim.x + threadIdx.x) >> 6;
    int lane = threadIdx.x & 63;
    if (g >= Gn) return;
    float cnt = (float)gcnt[g];
    float inv = 1.f / fmaxf(cnt, 1.f);
    float v = gsum[(size_t)g * 64 + lane] * inv * lin_w[lane];
    #pragma unroll
    for (int off = 32; off >= 1; off >>= 1) v += __shfl_xor(v, off);
    if (lane == 0) out[g] = v + lin_b[0];
}

extern "C" void kernel_launch(void* const* d_in, const int* in_sizes, int n_in,
                              void* d_out, int out_size, void* d_ws, size_t ws_size,
                              hipStream_t stream) {
    const float* x    = (const float*)d_in[0];
    const int*   ei   = (const int*)d_in[1];
    const int*   batch= (const int*)d_in[2];
    const float* W1   = (const float*)d_in[3];
    const float* a1s  = (const float*)d_in[4];
    const float* a1d  = (const float*)d_in[5];
    const float* b1   = (const float*)d_in[6];
    const float* W2   = (const float*)d_in[7];
    const float* a2s  = (const float*)d_in[8];
    const float* a2d  = (const float*)d_in[9];
    const float* b2   = (const float*)d_in[10];
    const float* W3   = (const float*)d_in[11];
    const float* a3s  = (const float*)d_in[12];
    const float* a3d  = (const float*)d_in[13];
    const float* b3   = (const float*)d_in[14];
    const float* lw   = (const float*)d_in[15];
    const float* lb   = (const float*)d_in[16];

    int N = in_sizes[0] / 128;
    int E = in_sizes[1] / 2;
    int G = out_size;
    int RT32 = (N + 31) >> 5;      // 32-row tiles (layers 1-2)
    int RT64 = (N + 63) >> 6;      // 64-row tiles (layer 3)
    int Np = ((N + 127) >> 7) * 128;
    int NB = (N + 1023) >> 10;     // scan blocks (<=64 supported)

    char* p = (char*)d_ws;
    auto alloc = [&](size_t bytes) {
        char* r = p;
        p += (bytes + 255) & ~(size_t)255;
        return r;
    };
    unsigned short* hbuf = (unsigned short*)alloc((size_t)Np * 256 * 2);  // bf16 GEMM output
    unsigned short* aggh = (unsigned short*)alloc((size_t)Np * 256 * 2);  // agg out hi plane
    unsigned short* aggl = (unsigned short*)alloc((size_t)Np * 256 * 2);  // agg out lo plane
    unsigned short* pB1h = (unsigned short*)alloc((size_t)128 * 256 * 2);
    unsigned short* pB1l = (unsigned short*)alloc((size_t)128 * 256 * 2);
    unsigned short* pB2h = (unsigned short*)alloc((size_t)256 * 256 * 2);
    unsigned short* pB2l = (unsigned short*)alloc((size_t)256 * 256 * 2);
    unsigned short* pB3h = (unsigned short*)alloc((size_t)256 * 64 * 2);
    unsigned short* pB3l = (unsigned short*)alloc((size_t)256 * 64 * 2);
    float* al_s  = (float*)alloc((size_t)N * 4 * 4);
    float* al_d  = (float*)alloc((size_t)N * 4 * 4);
    int* indptr  = (int*)alloc((size_t)(N + 1) * 4);
    int* counts  = (int*)alloc((size_t)N * 4);
    int* cursor  = (int*)alloc((size_t)N * 4);
    int* lex     = (int*)alloc((size_t)N * 4);
    int* bsums   = (int*)alloc((size_t)256 * 4);
    int* csr     = (int*)alloc((size_t)E * 4);
    float* gsum  = (float*)alloc((size_t)G * 64 * 4);
    int* gcnt    = (int*)alloc((size_t)G * 4);
    if ((size_t)(p - (char*)d_ws) > ws_size) return;  // workspace too small

    hipMemsetAsync(counts, 0, (size_t)N * 4, stream);
    hipMemsetAsync(gsum, 0, (size_t)G * 64 * 4, stream);
    hipMemsetAsync(gcnt, 0, (size_t)G * 4, stream);

    k_packB3<<<(14336 + 255) / 256, 256, 0, stream>>>(W1, W2, W3,
        pB1h, pB1l, pB2h, pB2l, pB3h, pB3l);

    int eb = (E + 255) / 256;
    k_count<<<eb, 256, 0, stream>>>(ei, E, counts);
    k_scan_local<<<NB, 256, 0, stream>>>(counts, lex, bsums, N);
    k_scan_add<<<(N + 1 + 255) / 256, 256, 0, stream>>>(lex, bsums, indptr, cursor, N, E, NB);
    k_scatter<<<eb, 256, 0, stream>>>(ei, E, cursor, csr);

    int wb = (N * 64 + 255) / 256;   // one wave per node

    // layer 1: 128 -> 256 (H=4, concat, ELU); A = x f32 (CONV); 32-row blocks
    k_mm<2, 1, 4, true, 128><<<dim3(RT32, 1), 256, 0, stream>>>(x, nullptr, nullptr,
        pB1h, pB1l, hbuf, a1s, a1d, al_s, al_d, N, 256);
    k_agg<4, true, false><<<wb, 256, 0, stream>>>(hbuf, al_s, al_d, indptr, csr, b1,
        aggh, aggl, nullptr, nullptr, nullptr, N);

    // layer 2: 256 -> 256 (H=4, concat, ELU); A pre-split; 32-row blocks
    k_mm<2, 1, 4, false, 256><<<dim3(RT32, 1), 256, 0, stream>>>(nullptr, aggh, aggl,
        pB2h, pB2l, hbuf, a2s, a2d, al_s, al_d, N, 256);
    k_agg<4, true, false><<<wb, 256, 0, stream>>>(hbuf, al_s, al_d, indptr, csr, b2,
        aggh, aggl, nullptr, nullptr, nullptr, N);

    // layer 3: 256 -> 64 (H=1) + fused mean-pool; 64-row blocks
    k_mm<1, 4, 1, false, 256><<<dim3(RT64, 1), 256, 0, stream>>>(nullptr, aggh, aggl,
        pB3h, pB3l, hbuf, a3s, a3d, al_s, al_d, N, 64);
    k_agg1<<<wb, 256, 0, stream>>>(hbuf, al_s, al_d, indptr, csr, b3,
        gsum, batch, gcnt, N);

    int fb = (G * 64 + 255) / 256;
    k_final<<<fb, 256, 0, stream>>>(gsum, gcnt, lw, lb, (float*)d_out, G);
}

// Round 13
// 406.045 us; speedup vs baseline: 1.0665x; 1.0665x over previous
//
#include <hip/hip_runtime.h>
#include <cstdint>
#include <cstddef>

#define NEG_SLOPE 0.2f

typedef __attribute__((ext_vector_type(8))) short short8;
typedef __attribute__((ext_vector_type(4))) float f32x4;

__device__ __forceinline__ float lrelu(float v) { return v > 0.f ? v : NEG_SLOPE * v; }

__device__ __forceinline__ unsigned short f2bf(float x) {
    unsigned u = __float_as_uint(x);
    u = (u + 0x7FFFu + ((u >> 16) & 1u)) >> 16;
    return (unsigned short)u;
}
__device__ __forceinline__ float bf2f(unsigned short h) {
    return __uint_as_float(((unsigned)h) << 16);
}

// trunc split: hi = top 16 bits, lo = bf16_trunc(x - hi). Must stay identical
// everywhere it is used (k_mm CONV path and k_agg split-store).
__device__ __forceinline__ void splitbf(float v, unsigned short& hb, unsigned short& lb) {
    unsigned u = __float_as_uint(v);
    hb = (unsigned short)(u >> 16);
    float hf = __uint_as_float(u & 0xFFFF0000u);
    float lf = v - hf;
    lb = (unsigned short)(__float_as_uint(lf) >> 16);
}

// ---------------- CSR build ----------------
__global__ void k_count(const int* __restrict__ ei, int E, int* __restrict__ counts) {
    int i = blockIdx.x * blockDim.x + threadIdx.x;
    if (i < E) atomicAdd(&counts[ei[E + i]], 1);
}

__global__ __launch_bounds__(256) void k_scan_local(const int* __restrict__ counts,
        int* __restrict__ local_ex, int* __restrict__ bsums, int Nn) {
    int base = blockIdx.x * 1024;
    int tid = threadIdx.x;
    int idx = base + tid * 4;
    int4 v = make_int4(0, 0, 0, 0);
    if (idx + 3 < Nn) {
        v = *reinterpret_cast<const int4*>(&counts[idx]);
    } else {
        if (idx + 0 < Nn) v.x = counts[idx + 0];
        if (idx + 1 < Nn) v.y = counts[idx + 1];
        if (idx + 2 < Nn) v.z = counts[idx + 2];
        if (idx + 3 < Nn) v.w = counts[idx + 3];
    }
    int t = v.x + v.y + v.z + v.w;
    int lane = tid & 63, wave = tid >> 6;
    int s = t;
    #pragma unroll
    for (int off = 1; off < 64; off <<= 1) {
        int u = __shfl_up(s, off);
        if (lane >= off) s += u;
    }
    __shared__ int wsum[4];
    if (lane == 63) wsum[wave] = s;
    __syncthreads();
    int wo = 0;
    #pragma unroll
    for (int wv = 0; wv < 4; ++wv) wo += (wv < wave) ? wsum[wv] : 0;
    int ex = wo + s - t;
    int4 o;
    o.x = ex; o.y = ex + v.x; o.z = ex + v.x + v.y; o.w = ex + v.x + v.y + v.z;
    if (idx + 3 < Nn) {
        *reinterpret_cast<int4*>(&local_ex[idx]) = o;
    } else {
        if (idx + 0 < Nn) local_ex[idx + 0] = o.x;
        if (idx + 1 < Nn) local_ex[idx + 1] = o.y;
        if (idx + 2 < Nn) local_ex[idx + 2] = o.z;
        if (idx + 3 < Nn) local_ex[idx + 3] = o.w;
    }
    if (tid == 255) bsums[blockIdx.x] = wo + s;
}

__global__ __launch_bounds__(256) void k_scan_add(const int* __restrict__ local_ex,
        const int* __restrict__ bsums, int* __restrict__ indptr, int* __restrict__ cursor,
        int Nn, int Etot, int NB) {
    __shared__ int pref[64];
    int tid = threadIdx.x;
    if (tid < 64) {
        int v = (tid < NB) ? bsums[tid] : 0;
        int s = v;
        #pragma unroll
        for (int off = 1; off < 64; off <<= 1) {
            int u = __shfl_up(s, off);
            if ((tid & 63) >= off) s += u;
        }
        pref[tid] = s - v;   // exclusive prefix
    }
    __syncthreads();
    int i = blockIdx.x * 256 + tid;
    if (i < Nn) {
        int val = local_ex[i] + pref[i >> 10];
        indptr[i] = val;
        cursor[i] = val;
    } else if (i == Nn) {
        indptr[Nn] = Etot;
    }
}

__global__ void k_scatter(const int* __restrict__ ei, int E, int* __restrict__ cursor,
                          int* __restrict__ csr_src) {
    int i = blockIdx.x * blockDim.x + threadIdx.x;
    if (i < E) {
        int s = ei[i], d = ei[E + i];
        int pos = atomicAdd(&cursor[d], 1);
        csr_src[pos] = s;
    }
}

// ---------------- pack B ----------------
__device__ __forceinline__ void packB_one(const float* __restrict__ W,
        unsigned short* __restrict__ Ph, unsigned short* __restrict__ Pl,
        int K, int M, int tid) {
    int KS8 = K >> 3;
    int col = tid / KS8;
    int k = (tid - col * KS8) << 3;
    short8 hv, lv;
    #pragma unroll
    for (int j = 0; j < 8; ++j) {
        float x = W[(size_t)(k + j) * M + col];
        unsigned short hb = f2bf(x);
        hv[j] = (short)hb;
        lv[j] = (short)f2bf(x - bf2f(hb));
    }
    int ct64 = col >> 6, c = col & 63;
    int fb = c >> 4, cl = c & 15;
    int ks = k >> 5, kg = (k >> 3) & 3;
    int lane = cl | (kg << 4);
    size_t off = (((size_t)ct64 * (K >> 5) + ks) * 4 + fb) * 64 + lane;
    *reinterpret_cast<short8*>(Ph + off * 8) = hv;
    *reinterpret_cast<short8*>(Pl + off * 8) = lv;
}

__global__ __launch_bounds__(256) void k_packB3(const float* __restrict__ W1,
        const float* __restrict__ W2, const float* __restrict__ W3,
        unsigned short* p1h, unsigned short* p1l,
        unsigned short* p2h, unsigned short* p2l,
        unsigned short* p3h, unsigned short* p3l) {
    int tid = blockIdx.x * 256 + threadIdx.x;
    if (tid < 4096)        packB_one(W1, p1h, p1l, 128, 256, tid);
    else if (tid < 12288)  packB_one(W2, p2h, p2l, 256, 256, tid - 4096);
    else if (tid < 14336)  packB_one(W3, p3h, p3l, 256, 64, tid - 12288);
}

// ---------------- split-bf16 MFMA GEMM ----------------
template<int AF, int WR, int WC, bool CONV, int K>
__global__ __launch_bounds__(256) void k_mm(const float* __restrict__ A,
        const unsigned short* __restrict__ Aph, const unsigned short* __restrict__ Apl,
        const unsigned short* __restrict__ Bh, const unsigned short* __restrict__ Bl,
        unsigned short* __restrict__ C, const float* __restrict__ a_src, const float* __restrict__ a_dst,
        float* __restrict__ al_s, float* __restrict__ al_d, int Nrows, int M) {
    constexpr int BF = 4;
    constexpr int BR = WR * AF * 16;
    constexpr int KS = K >> 5;
    int wave = threadIdx.x >> 6, lane = threadIdx.x & 63;
    int wr = wave / WC, wc = wave % WC;
    int rt = blockIdx.x;
    int ct64 = blockIdx.y * WC + wc;
    int rl = lane & 15, kg = lane >> 4;
    const short8* B8h = reinterpret_cast<const short8*>(Bh);
    const short8* B8l = reinterpret_cast<const short8*>(Bl);

    const float* aptr[AF];
    const unsigned short *ahp[AF], *alp[AF];
    #pragma unroll
    for (int f = 0; f < AF; ++f) {
        int row = rt * BR + wr * (AF * 16) + f * 16 + rl;
        if (row > Nrows - 1) row = Nrows - 1;
        if constexpr (CONV) {
            aptr[f] = A + (size_t)row * K + kg * 8;
        } else {
            ahp[f] = Aph + (size_t)row * K + kg * 8;
            alp[f] = Apl + (size_t)row * K + kg * 8;
        }
    }

    f32x4 acc[AF][BF];
    #pragma unroll
    for (int i = 0; i < AF; ++i)
        #pragma unroll
        for (int j = 0; j < BF; ++j)
            acc[i][j] = (f32x4){0.f, 0.f, 0.f, 0.f};

    #pragma unroll
    for (int ks = 0; ks < KS; ++ks) {
        short8 a_h[AF], a_l[AF], b_h[BF], b_l[BF];
        #pragma unroll
        for (int f = 0; f < AF; ++f) {
            if constexpr (CONV) {
                const float* ap = aptr[f] + ks * 32;
                float4 v0 = *reinterpret_cast<const float4*>(ap);
                float4 v1 = *reinterpret_cast<const float4*>(ap + 4);
                float vv[8] = {v0.x, v0.y, v0.z, v0.w, v1.x, v1.y, v1.z, v1.w};
                #pragma unroll
                for (int j = 0; j < 8; ++j) {
                    unsigned short hb, lb;
                    splitbf(vv[j], hb, lb);
                    a_h[f][j] = (short)hb;
                    a_l[f][j] = (short)lb;
                }
            } else {
                a_h[f] = *reinterpret_cast<const short8*>(ahp[f] + ks * 32);
                a_l[f] = *reinterpret_cast<const short8*>(alp[f] + ks * 32);
            }
        }
        #pragma unroll
        for (int f = 0; f < BF; ++f) {
            size_t off = (((size_t)ct64 * KS + ks) * 4 + f) * 64 + lane;
            b_h[f] = B8h[off]; b_l[f] = B8l[off];
        }
        #pragma unroll
        for (int i = 0; i < AF; ++i)
            #pragma unroll
            for (int j = 0; j < BF; ++j) {
                acc[i][j] = __builtin_amdgcn_mfma_f32_16x16x32_bf16(a_l[i], b_h[j], acc[i][j], 0, 0, 0);
                acc[i][j] = __builtin_amdgcn_mfma_f32_16x16x32_bf16(a_h[i], b_l[j], acc[i][j], 0, 0, 0);
                acc[i][j] = __builtin_amdgcn_mfma_f32_16x16x32_bf16(a_h[i], b_h[j], acc[i][j], 0, 0, 0);
            }
    }

    int H = M >> 6;
    int head = ct64;
    int col0 = ct64 * 64;
    int cl = lane & 15, rgrp = lane >> 4;

    float as_[BF], ad_[BF];
    #pragma unroll
    for (int j = 0; j < BF; ++j) {
        as_[j] = a_src[col0 + j * 16 + cl];
        ad_[j] = a_dst[col0 + j * 16 + cl];
    }

    #pragma unroll
    for (int i = 0; i < AF; ++i) {
        int rowb = rt * BR + wr * (AF * 16) + i * 16 + rgrp * 4;
        #pragma unroll
        for (int r = 0; r < 4; ++r) {
            float sv = acc[i][0][r] * as_[0] + acc[i][1][r] * as_[1]
                     + acc[i][2][r] * as_[2] + acc[i][3][r] * as_[3];
            float dv = acc[i][0][r] * ad_[0] + acc[i][1][r] * ad_[1]
                     + acc[i][2][r] * ad_[2] + acc[i][3][r] * ad_[3];
            #pragma unroll
            for (int o = 1; o < 16; o <<= 1) {
                sv += __shfl_xor(sv, o);
                dv += __shfl_xor(dv, o);
            }
            int row = rowb + r;
            if (row < Nrows) {
                unsigned short* cp = &C[(size_t)row * M + col0 + cl];
                cp[0]  = f2bf(acc[i][0][r]);
                cp[16] = f2bf(acc[i][1][r]);
                cp[32] = f2bf(acc[i][2][r]);
                cp[48] = f2bf(acc[i][3][r]);
                if (cl == 0) {
                    al_s[(size_t)row * H + head] = sv;
                    al_d[(size_t)row * H + head] = dv;
                }
            }
        }
    }
}

// ---------------- fused softmax + aggregate (wave per destination node) ----------------
// Group softmax (per-head lane groups), invden hoisted, 8-unrolled gather (R9 form).
// CAP=64: deg ~ Poisson(16) so P(deg>64) ~ 1e-18; fallback keeps correctness.
template <int H, bool ACT, bool POOL>    // TOT = H*64
__global__ __launch_bounds__(256) void k_agg(const unsigned short* __restrict__ hlin,
                      const float* __restrict__ al_s,
                      const float* __restrict__ al_d, const int* __restrict__ indptr,
                      const int* __restrict__ csr_src, const float* __restrict__ bias,
                      unsigned short* __restrict__ out_hi, unsigned short* __restrict__ out_lo,
                      float* __restrict__ outf, const int* __restrict__ batch,
                      int* __restrict__ gcnt, int Nn) {
    constexpr int TOT = H * 64;
    constexpr int VEC = TOT / 64;
    constexpr int CAP = 64;
    constexpr int GRPW = 64 / H;   // lanes per head group
    __shared__ float sp[4][CAP * H];
    __shared__ int   si[4][CAP];
    int w = threadIdx.x >> 6;
    int lane = threadIdx.x & 63;
    int node = (blockIdx.x * blockDim.x + threadIdx.x) >> 6;
    if (node >= Nn) return;
    int d = node;
    int p0 = indptr[d], p1 = indptr[d + 1];
    int deg = p1 - p0;
    int head = (lane * VEC) >> 6;       // == lane / GRPW

    float ad[H], e_self[H];
    if constexpr (H == 4) {
        float4 adv = *reinterpret_cast<const float4*>(&al_d[(size_t)d * 4]);
        float4 asv = *reinterpret_cast<const float4*>(&al_s[(size_t)d * 4]);
        ad[0] = adv.x; ad[1] = adv.y; ad[2] = adv.z; ad[3] = adv.w;
        e_self[0] = lrelu(asv.x + ad[0]); e_self[1] = lrelu(asv.y + ad[1]);
        e_self[2] = lrelu(asv.z + ad[2]); e_self[3] = lrelu(asv.w + ad[3]);
    } else {
        ad[0] = al_d[d];
        e_self[0] = lrelu(al_s[d] + ad[0]);
    }

    if (deg <= CAP) {
        // phase A: compute e per lane-edge (all heads), stash in LDS (single pass)
        {
            int l = lane;
            float e_h[H];
            if (l < deg) {
                int s = csr_src[p0 + l];
                si[w][l] = s;
                if constexpr (H == 4) {
                    float4 sv = *reinterpret_cast<const float4*>(&al_s[(size_t)s * 4]);
                    e_h[0] = lrelu(sv.x + ad[0]); e_h[1] = lrelu(sv.y + ad[1]);
                    e_h[2] = lrelu(sv.z + ad[2]); e_h[3] = lrelu(sv.w + ad[3]);
                } else {
                    e_h[0] = lrelu(al_s[s] + ad[0]);
                }
            } else {
                #pragma unroll
                for (int h = 0; h < H; ++h) e_h[h] = -1e30f;
            }
            #pragma unroll
            for (int h = 0; h < H; ++h) sp[w][l * H + h] = e_h[h];
        }
        // per-head group reduction: max
        int li = lane & (GRPW - 1);
        float mg = e_self[head];
        for (int l = li; l < CAP; l += GRPW)
            mg = fmaxf(mg, sp[w][l * H + head]);
        #pragma unroll
        for (int o = 1; o < GRPW; o <<= 1)
            mg = fmaxf(mg, __shfl_xor(mg, o));
        // exp + denom (own head only), pv written back raw
        float deng = 0.f;
        for (int l = li; l < CAP; l += GRPW) {
            float pv = __expf(sp[w][l * H + head] - mg);
            sp[w][l * H + head] = pv;
            deng += pv;
        }
        #pragma unroll
        for (int o = 1; o < GRPW; o <<= 1)
            deng += __shfl_xor(deng, o);
        float esx = __expf(e_self[head] - mg);
        deng += esx;
        float invden = 1.f / deng;

        // gather with raw weights; invden applied once at end
        float4 accv = make_float4(0.f, 0.f, 0.f, 0.f);
        {
            const unsigned short* hp = hlin + (size_t)d * TOT + lane * VEC;
            if constexpr (VEC == 4) {
                ushort4 hv = *reinterpret_cast<const ushort4*>(hp);
                accv.x = esx * bf2f(hv.x); accv.y = esx * bf2f(hv.y);
                accv.z = esx * bf2f(hv.z); accv.w = esx * bf2f(hv.w);
            } else {
                accv.x = esx * bf2f(hp[0]);
            }
        }
        int e = 0;
        for (; e + 8 <= deg; e += 8) {
            int s0 = si[w][e + 0], s1 = si[w][e + 1], s2 = si[w][e + 2], s3 = si[w][e + 3];
            int s4 = si[w][e + 4], s5 = si[w][e + 5], s6 = si[w][e + 6], s7 = si[w][e + 7];
            float a0 = sp[w][(e + 0) * H + head];
            float a1 = sp[w][(e + 1) * H + head];
            float a2 = sp[w][(e + 2) * H + head];
            float a3 = sp[w][(e + 3) * H + head];
            float a4 = sp[w][(e + 4) * H + head];
            float a5 = sp[w][(e + 5) * H + head];
            float a6 = sp[w][(e + 6) * H + head];
            float a7 = sp[w][(e + 7) * H + head];
            if constexpr (VEC == 4) {
                ushort4 r0 = *reinterpret_cast<const ushort4*>(hlin + (size_t)s0 * TOT + lane * 4);
                ushort4 r1 = *reinterpret_cast<const ushort4*>(hlin + (size_t)s1 * TOT + lane * 4);
                ushort4 r2 = *reinterpret_cast<const ushort4*>(hlin + (size_t)s2 * TOT + lane * 4);
                ushort4 r3 = *reinterpret_cast<const ushort4*>(hlin + (size_t)s3 * TOT + lane * 4);
                ushort4 r4 = *reinterpret_cast<const ushort4*>(hlin + (size_t)s4 * TOT + lane * 4);
                ushort4 r5 = *reinterpret_cast<const ushort4*>(hlin + (size_t)s5 * TOT + lane * 4);
                ushort4 r6 = *reinterpret_cast<const ushort4*>(hlin + (size_t)s6 * TOT + lane * 4);
                ushort4 r7 = *reinterpret_cast<const ushort4*>(hlin + (size_t)s7 * TOT + lane * 4);
                accv.x += a0*bf2f(r0.x) + a1*bf2f(r1.x) + a2*bf2f(r2.x) + a3*bf2f(r3.x)
                        + a4*bf2f(r4.x) + a5*bf2f(r5.x) + a6*bf2f(r6.x) + a7*bf2f(r7.x);
                accv.y += a0*bf2f(r0.y) + a1*bf2f(r1.y) + a2*bf2f(r2.y) + a3*bf2f(r3.y)
                        + a4*bf2f(r4.y) + a5*bf2f(r5.y) + a6*bf2f(r6.y) + a7*bf2f(r7.y);
                accv.z += a0*bf2f(r0.z) + a1*bf2f(r1.z) + a2*bf2f(r2.z) + a3*bf2f(r3.z)
                        + a4*bf2f(r4.z) + a5*bf2f(r5.z) + a6*bf2f(r6.z) + a7*bf2f(r7.z);
                accv.w += a0*bf2f(r0.w) + a1*bf2f(r1.w) + a2*bf2f(r2.w) + a3*bf2f(r3.w)
                        + a4*bf2f(r4.w) + a5*bf2f(r5.w) + a6*bf2f(r6.w) + a7*bf2f(r7.w);
            } else {
                float r0 = bf2f(hlin[(size_t)s0 * TOT + lane]);
                float r1 = bf2f(hlin[(size_t)s1 * TOT + lane]);
                float r2 = bf2f(hlin[(size_t)s2 * TOT + lane]);
                float r3 = bf2f(hlin[(size_t)s3 * TOT + lane]);
                float r4 = bf2f(hlin[(size_t)s4 * TOT + lane]);
                float r5 = bf2f(hlin[(size_t)s5 * TOT + lane]);
                float r6 = bf2f(hlin[(size_t)s6 * TOT + lane]);
                float r7 = bf2f(hlin[(size_t)s7 * TOT + lane]);
                accv.x += a0*r0 + a1*r1 + a2*r2 + a3*r3 + a4*r4 + a5*r5 + a6*r6 + a7*r7;
            }
        }
        for (; e + 4 <= deg; e += 4) {
            int s0 = si[w][e + 0], s1 = si[w][e + 1];
            int s2 = si[w][e + 2], s3 = si[w][e + 3];
            float a0 = sp[w][(e + 0) * H + head];
            float a1 = sp[w][(e + 1) * H + head];
            float a2 = sp[w][(e + 2) * H + head];
            float a3 = sp[w][(e + 3) * H + head];
            if constexpr (VEC == 4) {
                ushort4 r0 = *reinterpret_cast<const ushort4*>(hlin + (size_t)s0 * TOT + lane * 4);
                ushort4 r1 = *reinterpret_cast<const ushort4*>(hlin + (size_t)s1 * TOT + lane * 4);
                ushort4 r2 = *reinterpret_cast<const ushort4*>(hlin + (size_t)s2 * TOT + lane * 4);
                ushort4 r3 = *reinterpret_cast<const ushort4*>(hlin + (size_t)s3 * TOT + lane * 4);
                accv.x += a0*bf2f(r0.x) + a1*bf2f(r1.x) + a2*bf2f(r2.x) + a3*bf2f(r3.x);
                accv.y += a0*bf2f(r0.y) + a1*bf2f(r1.y) + a2*bf2f(r2.y) + a3*bf2f(r3.y);
                accv.z += a0*bf2f(r0.z) + a1*bf2f(r1.z) + a2*bf2f(r2.z) + a3*bf2f(r3.z);
                accv.w += a0*bf2f(r0.w) + a1*bf2f(r1.w) + a2*bf2f(r2.w) + a3*bf2f(r3.w);
            } else {
                float r0 = bf2f(hlin[(size_t)s0 * TOT + lane]);
                float r1 = bf2f(hlin[(size_t)s1 * TOT + lane]);
                float r2 = bf2f(hlin[(size_t)s2 * TOT + lane]);
                float r3 = bf2f(hlin[(size_t)s3 * TOT + lane]);
                accv.x += a0 * r0 + a1 * r1 + a2 * r2 + a3 * r3;
            }
        }
        for (; e < deg; ++e) {
            int s = si[w][e];
            float a = sp[w][e * H + head];
            if constexpr (VEC == 4) {
                ushort4 rv = *reinterpret_cast<const ushort4*>(hlin + (size_t)s * TOT + lane * 4);
                accv.x += a * bf2f(rv.x); accv.y += a * bf2f(rv.y);
                accv.z += a * bf2f(rv.z); accv.w += a * bf2f(rv.w);
            } else {
                accv.x += a * bf2f(hlin[(size_t)s * TOT + lane]);
            }
        }
        if constexpr (VEC == 4) {
            int c0 = lane * 4;
            accv.x = accv.x * invden + bias[c0 + 0];
            accv.y = accv.y * invden + bias[c0 + 1];
            accv.z = accv.z * invden + bias[c0 + 2];
            accv.w = accv.w * invden + bias[c0 + 3];
            if (ACT) {
                accv.x = accv.x > 0.f ? accv.x : expm1f(accv.x);
                accv.y = accv.y > 0.f ? accv.y : expm1f(accv.y);
                accv.z = accv.z > 0.f ? accv.z : expm1f(accv.z);
                accv.w = accv.w > 0.f ? accv.w : expm1f(accv.w);
            }
            ushort4 hv, lv;
            splitbf(accv.x, hv.x, lv.x);
            splitbf(accv.y, hv.y, lv.y);
            splitbf(accv.z, hv.z, lv.z);
            splitbf(accv.w, hv.w, lv.w);
            *reinterpret_cast<ushort4*>(&out_hi[(size_t)d * TOT + c0]) = hv;
            *reinterpret_cast<ushort4*>(&out_lo[(size_t)d * TOT + c0]) = lv;
        } else {
            float o = accv.x * invden + bias[lane];
            if (ACT) o = o > 0.f ? o : expm1f(o);
            if constexpr (POOL) {
                int g = batch[d];
                atomicAdd(&outf[(size_t)g * 64 + lane], o);
                if (lane == 0) atomicAdd(&gcnt[g], 1);
            } else {
                unsigned short hb, lb;
                splitbf(o, hb, lb);
                out_hi[(size_t)d * TOT + lane] = hb;
                out_lo[(size_t)d * TOT + lane] = lb;
            }
        }
        return;
    }

    // ---- fallback: deg > CAP, serial 3-pass (no LDS) ----
    {
        float adh = ad[head];
        float es = e_self[head];
        float m = es;
        for (int e = p0; e < p1; ++e) {
            int s = csr_src[e];
            m = fmaxf(m, lrelu(al_s[(size_t)s * H + head] + adh));
        }
        float den = __expf(es - m);
        for (int e = p0; e < p1; ++e) {
            int s = csr_src[e];
            den += __expf(lrelu(al_s[(size_t)s * H + head] + adh) - m);
        }
        den = 1.f / den;
        float accv[VEC] = {};
        {
            float alpha = __expf(es - m) * den;
            const unsigned short* hp = hlin + (size_t)d * TOT + lane * VEC;
            #pragma unroll
            for (int v = 0; v < VEC; ++v) accv[v] = alpha * bf2f(hp[v]);
        }
        for (int e = p0; e < p1; ++e) {
            int s = csr_src[e];
            float alpha = __expf(lrelu(al_s[(size_t)s * H + head] + adh) - m) * den;
            const unsigned short* hp = hlin + (size_t)s * TOT + lane * VEC;
            #pragma unroll
            for (int v = 0; v < VEC; ++v) accv[v] += alpha * bf2f(hp[v]);
        }
        #pragma unroll
        for (int v = 0; v < VEC; ++v) {
            int c = lane * VEC + v;
            float o = accv[v] + bias[c];
            if (ACT) o = o > 0.f ? o : expm1f(o);
            accv[v] = o;
        }
        if constexpr (POOL) {
            int g = batch[d];
            atomicAdd(&outf[(size_t)g * 64 + lane], accv[0]);
            if (lane == 0) atomicAdd(&gcnt[g], 1);
        } else {
            #pragma unroll
            for (int v = 0; v < VEC; ++v) {
                unsigned short hb, lb;
                splitbf(accv[v], hb, lb);
                out_hi[(size_t)d * TOT + lane * VEC + v] = hb;
                out_lo[(size_t)d * TOT + lane * VEC + v] = lb;
            }
        }
    }
}

// ---------------- final linear ----------------
__global__ void k_final(const float* __restrict__ gsum, const int* __restrict__ gcnt,
                        const float* __restrict__ lin_w, const float* __restrict__ lin_b,
                        float* __restrict__ out, int Gn) {
    int g = (blockIdx.x * blockDim.x + threadIdx.x) >> 6;
    int lane = threadIdx.x & 63;
    if (g >= Gn) return;
    float cnt = (float)gcnt[g];
    float inv = 1.f / fmaxf(cnt, 1.f);
    float v = gsum[(size_t)g * 64 + lane] * inv * lin_w[lane];
    #pragma unroll
    for (int off = 32; off >= 1; off >>= 1) v += __shfl_xor(v, off);
    if (lane == 0) out[g] = v + lin_b[0];
}

extern "C" void kernel_launch(void* const* d_in, const int* in_sizes, int n_in,
                              void* d_out, int out_size, void* d_ws, size_t ws_size,
                              hipStream_t stream) {
    const float* x    = (const float*)d_in[0];
    const int*   ei   = (const int*)d_in[1];
    const int*   batch= (const int*)d_in[2];
    const float* W1   = (const float*)d_in[3];
    const float* a1s  = (const float*)d_in[4];
    const float* a1d  = (const float*)d_in[5];
    const float* b1   = (const float*)d_in[6];
    const float* W2   = (const float*)d_in[7];
    const float* a2s  = (const float*)d_in[8];
    const float* a2d  = (const float*)d_in[9];
    const float* b2   = (const float*)d_in[10];
    const float* W3   = (const float*)d_in[11];
    const float* a3s  = (const float*)d_in[12];
    const float* a3d  = (const float*)d_in[13];
    const float* b3   = (const float*)d_in[14];
    const float* lw   = (const float*)d_in[15];
    const float* lb   = (const float*)d_in[16];

    int N = in_sizes[0] / 128;
    int E = in_sizes[1] / 2;
    int G = out_size;
    int RT32 = (N + 31) >> 5;      // 32-row tiles (layers 1-2)
    int RT64 = (N + 63) >> 6;      // 64-row tiles (layer 3)
    int Np = ((N + 127) >> 7) * 128;
    int NB = (N + 1023) >> 10;     // scan blocks (<=64 supported)

    char* p = (char*)d_ws;
    auto alloc = [&](size_t bytes) {
        char* r = p;
        p += (bytes + 255) & ~(size_t)255;
        return r;
    };
    unsigned short* hbuf = (unsigned short*)alloc((size_t)Np * 256 * 2);  // bf16 GEMM output
    unsigned short* aggh = (unsigned short*)alloc((size_t)Np * 256 * 2);  // agg out hi plane
    unsigned short* aggl = (unsigned short*)alloc((size_t)Np * 256 * 2);  // agg out lo plane
    unsigned short* pB1h = (unsigned short*)alloc((size_t)128 * 256 * 2);
    unsigned short* pB1l = (unsigned short*)alloc((size_t)128 * 256 * 2);
    unsigned short* pB2h = (unsigned short*)alloc((size_t)256 * 256 * 2);
    unsigned short* pB2l = (unsigned short*)alloc((size_t)256 * 256 * 2);
    unsigned short* pB3h = (unsigned short*)alloc((size_t)256 * 64 * 2);
    unsigned short* pB3l = (unsigned short*)alloc((size_t)256 * 64 * 2);
    float* al_s  = (float*)alloc((size_t)N * 4 * 4);
    float* al_d  = (float*)alloc((size_t)N * 4 * 4);
    int* indptr  = (int*)alloc((size_t)(N + 1) * 4);
    int* counts  = (int*)alloc((size_t)N * 4);
    int* cursor  = (int*)alloc((size_t)N * 4);
    int* lex     = (int*)alloc((size_t)N * 4);
    int* bsums   = (int*)alloc((size_t)256 * 4);
    int* csr     = (int*)alloc((size_t)E * 4);
    float* gsum  = (float*)alloc((size_t)G * 64 * 4);
    int* gcnt    = (int*)alloc((size_t)G * 4);
    if ((size_t)(p - (char*)d_ws) > ws_size) return;  // workspace too small

    hipMemsetAsync(counts, 0, (size_t)N * 4, stream);
    hipMemsetAsync(gsum, 0, (size_t)G * 64 * 4, stream);
    hipMemsetAsync(gcnt, 0, (size_t)G * 4, stream);

    k_packB3<<<(14336 + 255) / 256, 256, 0, stream>>>(W1, W2, W3,
        pB1h, pB1l, pB2h, pB2l, pB3h, pB3l);

    int eb = (E + 255) / 256;
    k_count<<<eb, 256, 0, stream>>>(ei, E, counts);
    k_scan_local<<<NB, 256, 0, stream>>>(counts, lex, bsums, N);
    k_scan_add<<<(N + 1 + 255) / 256, 256, 0, stream>>>(lex, bsums, indptr, cursor, N, E, NB);
    k_scatter<<<eb, 256, 0, stream>>>(ei, E, cursor, csr);

    int wb = (N * 64 + 255) / 256;   // one wave per node

    // layer 1: 128 -> 256 (H=4, concat, ELU); A = x f32 (CONV); 32-row blocks
    k_mm<2, 1, 4, true, 128><<<dim3(RT32, 1), 256, 0, stream>>>(x, nullptr, nullptr,
        pB1h, pB1l, hbuf, a1s, a1d, al_s, al_d, N, 256);
    k_agg<4, true, false><<<wb, 256, 0, stream>>>(hbuf, al_s, al_d, indptr, csr, b1,
        aggh, aggl, nullptr, nullptr, nullptr, N);

    // layer 2: 256 -> 256 (H=4, concat, ELU); A pre-split; 32-row blocks
    k_mm<2, 1, 4, false, 256><<<dim3(RT32, 1), 256, 0, stream>>>(nullptr, aggh, aggl,
        pB2h, pB2l, hbuf, a2s, a2d, al_s, al_d, N, 256);
    k_agg<4, true, false><<<wb, 256, 0, stream>>>(hbuf, al_s, al_d, indptr, csr, b2,
        aggh, aggl, nullptr, nullptr, nullptr, N);

    // layer 3: 256 -> 64 (H=1) + fused mean-pool; 64-row blocks
    k_mm<1, 4, 1, false, 256><<<dim3(RT64, 1), 256, 0, stream>>>(nullptr, aggh, aggl,
        pB3h, pB3l, hbuf, a3s, a3d, al_s, al_d, N, 64);
    k_agg<1, false, true><<<wb, 256, 0, stream>>>(hbuf, al_s, al_d, indptr, csr, b3,
        nullptr, nullptr, gsum, batch, gcnt, N);

    int fb = (G * 64 + 255) / 256;
    k_final<<<fb, 256, 0, stream>>>(gsum, gcnt, lw, lb, (float*)d_out, G);
}

// Round 14
// 399.247 us; speedup vs baseline: 1.0847x; 1.0170x over previous
//
#include <hip/hip_runtime.h>
#include <cstdint>
#include <cstddef>

#define NEG_SLOPE 0.2f

typedef __attribute__((ext_vector_type(8))) short short8;
typedef __attribute__((ext_vector_type(4))) float f32x4;

__device__ __forceinline__ float lrelu(float v) { return v > 0.f ? v : NEG_SLOPE * v; }

__device__ __forceinline__ unsigned short f2bf(float x) {
    unsigned u = __float_as_uint(x);
    u = (u + 0x7FFFu + ((u >> 16) & 1u)) >> 16;
    return (unsigned short)u;
}
__device__ __forceinline__ float bf2f(unsigned short h) {
    return __uint_as_float(((unsigned)h) << 16);
}

// trunc split: hi = top 16 bits, lo = bf16_trunc(x - hi). Must stay identical
// everywhere it is used (k_mm CONV path and k_agg split-store).
__device__ __forceinline__ void splitbf(float v, unsigned short& hb, unsigned short& lb) {
    unsigned u = __float_as_uint(v);
    hb = (unsigned short)(u >> 16);
    float hf = __uint_as_float(u & 0xFFFF0000u);
    float lf = v - hf;
    lb = (unsigned short)(__float_as_uint(lf) >> 16);
}

// ---------------- CSR build ----------------
__global__ void k_count(const int* __restrict__ ei, int E, int* __restrict__ counts) {
    int i = blockIdx.x * blockDim.x + threadIdx.x;
    if (i < E) atomicAdd(&counts[ei[E + i]], 1);
}

__global__ __launch_bounds__(256) void k_scan_local(const int* __restrict__ counts,
        int* __restrict__ local_ex, int* __restrict__ bsums, int Nn) {
    int base = blockIdx.x * 1024;
    int tid = threadIdx.x;
    int idx = base + tid * 4;
    int4 v = make_int4(0, 0, 0, 0);
    if (idx + 3 < Nn) {
        v = *reinterpret_cast<const int4*>(&counts[idx]);
    } else {
        if (idx + 0 < Nn) v.x = counts[idx + 0];
        if (idx + 1 < Nn) v.y = counts[idx + 1];
        if (idx + 2 < Nn) v.z = counts[idx + 2];
        if (idx + 3 < Nn) v.w = counts[idx + 3];
    }
    int t = v.x + v.y + v.z + v.w;
    int lane = tid & 63, wave = tid >> 6;
    int s = t;
    #pragma unroll
    for (int off = 1; off < 64; off <<= 1) {
        int u = __shfl_up(s, off);
        if (lane >= off) s += u;
    }
    __shared__ int wsum[4];
    if (lane == 63) wsum[wave] = s;
    __syncthreads();
    int wo = 0;
    #pragma unroll
    for (int wv = 0; wv < 4; ++wv) wo += (wv < wave) ? wsum[wv] : 0;
    int ex = wo + s - t;
    int4 o;
    o.x = ex; o.y = ex + v.x; o.z = ex + v.x + v.y; o.w = ex + v.x + v.y + v.z;
    if (idx + 3 < Nn) {
        *reinterpret_cast<int4*>(&local_ex[idx]) = o;
    } else {
        if (idx + 0 < Nn) local_ex[idx + 0] = o.x;
        if (idx + 1 < Nn) local_ex[idx + 1] = o.y;
        if (idx + 2 < Nn) local_ex[idx + 2] = o.z;
        if (idx + 3 < Nn) local_ex[idx + 3] = o.w;
    }
    if (tid == 255) bsums[blockIdx.x] = wo + s;
}

__global__ __launch_bounds__(256) void k_scan_add(const int* __restrict__ local_ex,
        const int* __restrict__ bsums, int* __restrict__ indptr, int* __restrict__ cursor,
        int Nn, int Etot, int NB) {
    __shared__ int pref[64];
    int tid = threadIdx.x;
    if (tid < 64) {
        int v = (tid < NB) ? bsums[tid] : 0;
        int s = v;
        #pragma unroll
        for (int off = 1; off < 64; off <<= 1) {
            int u = __shfl_up(s, off);
            if ((tid & 63) >= off) s += u;
        }
        pref[tid] = s - v;   // exclusive prefix
    }
    __syncthreads();
    int i = blockIdx.x * 256 + tid;
    if (i < Nn) {
        int val = local_ex[i] + pref[i >> 10];
        indptr[i] = val;
        cursor[i] = val;
    } else if (i == Nn) {
        indptr[Nn] = Etot;
    }
}

__global__ void k_scatter(const int* __restrict__ ei, int E, int* __restrict__ cursor,
                          int* __restrict__ csr_src) {
    int i = blockIdx.x * blockDim.x + threadIdx.x;
    if (i < E) {
        int s = ei[i], d = ei[E + i];
        int pos = atomicAdd(&cursor[d], 1);
        csr_src[pos] = s;
    }
}

// ---------------- pack B ----------------
__device__ __forceinline__ void packB_one(const float* __restrict__ W,
        unsigned short* __restrict__ Ph, unsigned short* __restrict__ Pl,
        int K, int M, int tid) {
    int KS8 = K >> 3;
    int col = tid / KS8;
    int k = (tid - col * KS8) << 3;
    short8 hv, lv;
    #pragma unroll
    for (int j = 0; j < 8; ++j) {
        float x = W[(size_t)(k + j) * M + col];
        unsigned short hb = f2bf(x);
        hv[j] = (short)hb;
        lv[j] = (short)f2bf(x - bf2f(hb));
    }
    int ct64 = col >> 6, c = col & 63;
    int fb = c >> 4, cl = c & 15;
    int ks = k >> 5, kg = (k >> 3) & 3;
    int lane = cl | (kg << 4);
    size_t off = (((size_t)ct64 * (K >> 5) + ks) * 4 + fb) * 64 + lane;
    *reinterpret_cast<short8*>(Ph + off * 8) = hv;
    *reinterpret_cast<short8*>(Pl + off * 8) = lv;
}

__global__ __launch_bounds__(256) void k_packB3(const float* __restrict__ W1,
        const float* __restrict__ W2, const float* __restrict__ W3,
        unsigned short* p1h, unsigned short* p1l,
        unsigned short* p2h, unsigned short* p2l,
        unsigned short* p3h, unsigned short* p3l) {
    int tid = blockIdx.x * 256 + threadIdx.x;
    if (tid < 4096)        packB_one(W1, p1h, p1l, 128, 256, tid);
    else if (tid < 12288)  packB_one(W2, p2h, p2l, 256, 256, tid - 4096);
    else if (tid < 14336)  packB_one(W3, p3h, p3l, 256, 64, tid - 12288);
}

// ---------------- split-bf16 MFMA GEMM ----------------
template<int AF, int WR, int WC, bool CONV, int K>
__global__ __launch_bounds__(256) void k_mm(const float* __restrict__ A,
        const unsigned short* __restrict__ Aph, const unsigned short* __restrict__ Apl,
        const unsigned short* __restrict__ Bh, const unsigned short* __restrict__ Bl,
        unsigned short* __restrict__ C, const float* __restrict__ a_src, const float* __restrict__ a_dst,
        float* __restrict__ al_s, float* __restrict__ al_d, int Nrows, int M) {
    constexpr int BF = 4;
    constexpr int BR = WR * AF * 16;
    constexpr int KS = K >> 5;
    int wave = threadIdx.x >> 6, lane = threadIdx.x & 63;
    int wr = wave / WC, wc = wave % WC;
    int rt = blockIdx.x;
    int ct64 = blockIdx.y * WC + wc;
    int rl = lane & 15, kg = lane >> 4;
    const short8* B8h = reinterpret_cast<const short8*>(Bh);
    const short8* B8l = reinterpret_cast<const short8*>(Bl);

    const float* aptr[AF];
    const unsigned short *ahp[AF], *alp[AF];
    #pragma unroll
    for (int f = 0; f < AF; ++f) {
        int row = rt * BR + wr * (AF * 16) + f * 16 + rl;
        if (row > Nrows - 1) row = Nrows - 1;
        if constexpr (CONV) {
            aptr[f] = A + (size_t)row * K + kg * 8;
        } else {
            ahp[f] = Aph + (size_t)row * K + kg * 8;
            alp[f] = Apl + (size_t)row * K + kg * 8;
        }
    }

    f32x4 acc[AF][BF];
    #pragma unroll
    for (int i = 0; i < AF; ++i)
        #pragma unroll
        for (int j = 0; j < BF; ++j)
            acc[i][j] = (f32x4){0.f, 0.f, 0.f, 0.f};

    #pragma unroll
    for (int ks = 0; ks < KS; ++ks) {
        short8 a_h[AF], a_l[AF], b_h[BF], b_l[BF];
        #pragma unroll
        for (int f = 0; f < AF; ++f) {
            if constexpr (CONV) {
                const float* ap = aptr[f] + ks * 32;
                float4 v0 = *reinterpret_cast<const float4*>(ap);
                float4 v1 = *reinterpret_cast<const float4*>(ap + 4);
                float vv[8] = {v0.x, v0.y, v0.z, v0.w, v1.x, v1.y, v1.z, v1.w};
                #pragma unroll
                for (int j = 0; j < 8; ++j) {
                    unsigned short hb, lb;
                    splitbf(vv[j], hb, lb);
                    a_h[f][j] = (short)hb;
                    a_l[f][j] = (short)lb;
                }
            } else {
                a_h[f] = *reinterpret_cast<const short8*>(ahp[f] + ks * 32);
                a_l[f] = *reinterpret_cast<const short8*>(alp[f] + ks * 32);
            }
        }
        #pragma unroll
        for (int f = 0; f < BF; ++f) {
            size_t off = (((size_t)ct64 * KS + ks) * 4 + f) * 64 + lane;
            b_h[f] = B8h[off]; b_l[f] = B8l[off];
        }
        #pragma unroll
        for (int i = 0; i < AF; ++i)
            #pragma unroll
            for (int j = 0; j < BF; ++j) {
                acc[i][j] = __builtin_amdgcn_mfma_f32_16x16x32_bf16(a_l[i], b_h[j], acc[i][j], 0, 0, 0);
                acc[i][j] = __builtin_amdgcn_mfma_f32_16x16x32_bf16(a_h[i], b_l[j], acc[i][j], 0, 0, 0);
                acc[i][j] = __builtin_amdgcn_mfma_f32_16x16x32_bf16(a_h[i], b_h[j], acc[i][j], 0, 0, 0);
            }
    }

    int H = M >> 6;
    int head = ct64;
    int col0 = ct64 * 64;
    int cl = lane & 15, rgrp = lane >> 4;

    float as_[BF], ad_[BF];
    #pragma unroll
    for (int j = 0; j < BF; ++j) {
        as_[j] = a_src[col0 + j * 16 + cl];
        ad_[j] = a_dst[col0 + j * 16 + cl];
    }

    #pragma unroll
    for (int i = 0; i < AF; ++i) {
        int rowb = rt * BR + wr * (AF * 16) + i * 16 + rgrp * 4;
        #pragma unroll
        for (int r = 0; r < 4; ++r) {
            float sv = acc[i][0][r] * as_[0] + acc[i][1][r] * as_[1]
                     + acc[i][2][r] * as_[2] + acc[i][3][r] * as_[3];
            float dv = acc[i][0][r] * ad_[0] + acc[i][1][r] * ad_[1]
                     + acc[i][2][r] * ad_[2] + acc[i][3][r] * ad_[3];
            #pragma unroll
            for (int o = 1; o < 16; o <<= 1) {
                sv += __shfl_xor(sv, o);
                dv += __shfl_xor(dv, o);
            }
            int row = rowb + r;
            if (row < Nrows) {
                unsigned short* cp = &C[(size_t)row * M + col0 + cl];
                cp[0]  = f2bf(acc[i][0][r]);
                cp[16] = f2bf(acc[i][1][r]);
                cp[32] = f2bf(acc[i][2][r]);
                cp[48] = f2bf(acc[i][3][r]);
                if (cl == 0) {
                    al_s[(size_t)row * H + head] = sv;
                    al_d[(size_t)row * H + head] = dv;
                }
            }
        }
    }
}

// ---------------- fused softmax + aggregate (wave per destination node) ----------------
// Group softmax (per-head lane groups), invden hoisted, 8-unrolled gather (H=4) /
// 16-unrolled gather (H=1: latency-bound, deg~17 -> 1-2 rounds). CAP=64.
template <int H, bool ACT, bool POOL>    // TOT = H*64
__global__ __launch_bounds__(256) void k_agg(const unsigned short* __restrict__ hlin,
                      const float* __restrict__ al_s,
                      const float* __restrict__ al_d, const int* __restrict__ indptr,
                      const int* __restrict__ csr_src, const float* __restrict__ bias,
                      unsigned short* __restrict__ out_hi, unsigned short* __restrict__ out_lo,
                      float* __restrict__ outf, const int* __restrict__ batch,
                      int* __restrict__ gcnt, int Nn) {
    constexpr int TOT = H * 64;
    constexpr int VEC = TOT / 64;
    constexpr int CAP = 64;
    constexpr int GRPW = 64 / H;   // lanes per head group
    __shared__ float sp[4][CAP * H];
    __shared__ int   si[4][CAP];
    int w = threadIdx.x >> 6;
    int lane = threadIdx.x & 63;
    int node = (blockIdx.x * blockDim.x + threadIdx.x) >> 6;
    if (node >= Nn) return;
    int d = node;
    int p0 = indptr[d], p1 = indptr[d + 1];
    int deg = p1 - p0;
    int head = (lane * VEC) >> 6;       // == lane / GRPW

    float ad[H], e_self[H];
    if constexpr (H == 4) {
        float4 adv = *reinterpret_cast<const float4*>(&al_d[(size_t)d * 4]);
        float4 asv = *reinterpret_cast<const float4*>(&al_s[(size_t)d * 4]);
        ad[0] = adv.x; ad[1] = adv.y; ad[2] = adv.z; ad[3] = adv.w;
        e_self[0] = lrelu(asv.x + ad[0]); e_self[1] = lrelu(asv.y + ad[1]);
        e_self[2] = lrelu(asv.z + ad[2]); e_self[3] = lrelu(asv.w + ad[3]);
    } else {
        ad[0] = al_d[d];
        e_self[0] = lrelu(al_s[d] + ad[0]);
    }

    if (deg <= CAP) {
        // phase A: compute e per lane-edge (all heads), stash in LDS (single pass)
        {
            int l = lane;
            float e_h[H];
            if (l < deg) {
                int s = csr_src[p0 + l];
                si[w][l] = s;
                if constexpr (H == 4) {
                    float4 sv = *reinterpret_cast<const float4*>(&al_s[(size_t)s * 4]);
                    e_h[0] = lrelu(sv.x + ad[0]); e_h[1] = lrelu(sv.y + ad[1]);
                    e_h[2] = lrelu(sv.z + ad[2]); e_h[3] = lrelu(sv.w + ad[3]);
                } else {
                    e_h[0] = lrelu(al_s[s] + ad[0]);
                }
            } else {
                #pragma unroll
                for (int h = 0; h < H; ++h) e_h[h] = -1e30f;
            }
            #pragma unroll
            for (int h = 0; h < H; ++h) sp[w][l * H + h] = e_h[h];
        }
        // per-head group reduction: max
        int li = lane & (GRPW - 1);
        float mg = e_self[head];
        for (int l = li; l < CAP; l += GRPW)
            mg = fmaxf(mg, sp[w][l * H + head]);
        #pragma unroll
        for (int o = 1; o < GRPW; o <<= 1)
            mg = fmaxf(mg, __shfl_xor(mg, o));
        // exp + denom (own head only), pv written back raw
        float deng = 0.f;
        for (int l = li; l < CAP; l += GRPW) {
            float pv = __expf(sp[w][l * H + head] - mg);
            sp[w][l * H + head] = pv;
            deng += pv;
        }
        #pragma unroll
        for (int o = 1; o < GRPW; o <<= 1)
            deng += __shfl_xor(deng, o);
        float esx = __expf(e_self[head] - mg);
        deng += esx;
        float invden = 1.f / deng;

        // gather with raw weights; invden applied once at end
        float4 accv = make_float4(0.f, 0.f, 0.f, 0.f);
        {
            const unsigned short* hp = hlin + (size_t)d * TOT + lane * VEC;
            if constexpr (VEC == 4) {
                ushort4 hv = *reinterpret_cast<const ushort4*>(hp);
                accv.x = esx * bf2f(hv.x); accv.y = esx * bf2f(hv.y);
                accv.z = esx * bf2f(hv.z); accv.w = esx * bf2f(hv.w);
            } else {
                accv.x = esx * bf2f(hp[0]);
            }
        }
        if constexpr (VEC == 4) {
            int e = 0;
            for (; e + 8 <= deg; e += 8) {
                int s0 = si[w][e + 0], s1 = si[w][e + 1], s2 = si[w][e + 2], s3 = si[w][e + 3];
                int s4 = si[w][e + 4], s5 = si[w][e + 5], s6 = si[w][e + 6], s7 = si[w][e + 7];
                float a0 = sp[w][(e + 0) * H + head];
                float a1 = sp[w][(e + 1) * H + head];
                float a2 = sp[w][(e + 2) * H + head];
                float a3 = sp[w][(e + 3) * H + head];
                float a4 = sp[w][(e + 4) * H + head];
                float a5 = sp[w][(e + 5) * H + head];
                float a6 = sp[w][(e + 6) * H + head];
                float a7 = sp[w][(e + 7) * H + head];
                ushort4 r0 = *reinterpret_cast<const ushort4*>(hlin + (size_t)s0 * TOT + lane * 4);
                ushort4 r1 = *reinterpret_cast<const ushort4*>(hlin + (size_t)s1 * TOT + lane * 4);
                ushort4 r2 = *reinterpret_cast<const ushort4*>(hlin + (size_t)s2 * TOT + lane * 4);
                ushort4 r3 = *reinterpret_cast<const ushort4*>(hlin + (size_t)s3 * TOT + lane * 4);
                ushort4 r4 = *reinterpret_cast<const ushort4*>(hlin + (size_t)s4 * TOT + lane * 4);
                ushort4 r5 = *reinterpret_cast<const ushort4*>(hlin + (size_t)s5 * TOT + lane * 4);
                ushort4 r6 = *reinterpret_cast<const ushort4*>(hlin + (size_t)s6 * TOT + lane * 4);
                ushort4 r7 = *reinterpret_cast<const ushort4*>(hlin + (size_t)s7 * TOT + lane * 4);
                accv.x += a0*bf2f(r0.x) + a1*bf2f(r1.x) + a2*bf2f(r2.x) + a3*bf2f(r3.x)
                        + a4*bf2f(r4.x) + a5*bf2f(r5.x) + a6*bf2f(r6.x) + a7*bf2f(r7.x);
                accv.y += a0*bf2f(r0.y) + a1*bf2f(r1.y) + a2*bf2f(r2.y) + a3*bf2f(r3.y)
                        + a4*bf2f(r4.y) + a5*bf2f(r5.y) + a6*bf2f(r6.y) + a7*bf2f(r7.y);
                accv.z += a0*bf2f(r0.z) + a1*bf2f(r1.z) + a2*bf2f(r2.z) + a3*bf2f(r3.z)
                        + a4*bf2f(r4.z) + a5*bf2f(r5.z) + a6*bf2f(r6.z) + a7*bf2f(r7.z);
                accv.w += a0*bf2f(r0.w) + a1*bf2f(r1.w) + a2*bf2f(r2.w) + a3*bf2f(r3.w)
                        + a4*bf2f(r4.w) + a5*bf2f(r5.w) + a6*bf2f(r6.w) + a7*bf2f(r7.w);
            }
            for (; e + 4 <= deg; e += 4) {
                int s0 = si[w][e + 0], s1 = si[w][e + 1];
                int s2 = si[w][e + 2], s3 = si[w][e + 3];
                float a0 = sp[w][(e + 0) * H + head];
                float a1 = sp[w][(e + 1) * H + head];
                float a2 = sp[w][(e + 2) * H + head];
                float a3 = sp[w][(e + 3) * H + head];
                ushort4 r0 = *reinterpret_cast<const ushort4*>(hlin + (size_t)s0 * TOT + lane * 4);
                ushort4 r1 = *reinterpret_cast<const ushort4*>(hlin + (size_t)s1 * TOT + lane * 4);
                ushort4 r2 = *reinterpret_cast<const ushort4*>(hlin + (size_t)s2 * TOT + lane * 4);
                ushort4 r3 = *reinterpret_cast<const ushort4*>(hlin + (size_t)s3 * TOT + lane * 4);
                accv.x += a0*bf2f(r0.x) + a1*bf2f(r1.x) + a2*bf2f(r2.x) + a3*bf2f(r3.x);
                accv.y += a0*bf2f(r0.y) + a1*bf2f(r1.y) + a2*bf2f(r2.y) + a3*bf2f(r3.y);
                accv.z += a0*bf2f(r0.z) + a1*bf2f(r1.z) + a2*bf2f(r2.z) + a3*bf2f(r3.z);
                accv.w += a0*bf2f(r0.w) + a1*bf2f(r1.w) + a2*bf2f(r2.w) + a3*bf2f(r3.w);
            }
            for (; e < deg; ++e) {
                int s = si[w][e];
                float a = sp[w][e * H + head];
                ushort4 rv = *reinterpret_cast<const ushort4*>(hlin + (size_t)s * TOT + lane * 4);
                accv.x += a * bf2f(rv.x); accv.y += a * bf2f(rv.y);
                accv.z += a * bf2f(rv.z); accv.w += a * bf2f(rv.w);
            }
        } else {
            // H=1: 16-deep unroll — deg~17 completes in 1-2 rounds (latency-bound path)
            int e = 0;
            for (; e + 16 <= deg; e += 16) {
                float part = 0.f;
                #pragma unroll
                for (int j = 0; j < 16; ++j) {
                    int s = si[w][e + j];
                    float a = sp[w][e + j];
                    part += a * bf2f(hlin[(size_t)s * TOT + lane]);
                }
                accv.x += part;
            }
            if (e < deg) {
                int rem = deg - e;   // 1..15
                unsigned short rr[16]; float aa[16];
                #pragma unroll
                for (int j = 0; j < 16; ++j) {
                    int idx = e + j;
                    bool vld = j < rem;
                    int s = vld ? si[w][idx] : d;
                    aa[j] = vld ? sp[w][idx] : 0.f;
                    rr[j] = hlin[(size_t)s * TOT + lane];
                }
                float part = 0.f;
                #pragma unroll
                for (int j = 0; j < 16; ++j) part += aa[j] * bf2f(rr[j]);
                accv.x += part;
            }
        }
        if constexpr (VEC == 4) {
            int c0 = lane * 4;
            accv.x = accv.x * invden + bias[c0 + 0];
            accv.y = accv.y * invden + bias[c0 + 1];
            accv.z = accv.z * invden + bias[c0 + 2];
            accv.w = accv.w * invden + bias[c0 + 3];
            if (ACT) {
                accv.x = accv.x > 0.f ? accv.x : expm1f(accv.x);
                accv.y = accv.y > 0.f ? accv.y : expm1f(accv.y);
                accv.z = accv.z > 0.f ? accv.z : expm1f(accv.z);
                accv.w = accv.w > 0.f ? accv.w : expm1f(accv.w);
            }
            ushort4 hv, lv;
            splitbf(accv.x, hv.x, lv.x);
            splitbf(accv.y, hv.y, lv.y);
            splitbf(accv.z, hv.z, lv.z);
            splitbf(accv.w, hv.w, lv.w);
            *reinterpret_cast<ushort4*>(&out_hi[(size_t)d * TOT + c0]) = hv;
            *reinterpret_cast<ushort4*>(&out_lo[(size_t)d * TOT + c0]) = lv;
        } else {
            float o = accv.x * invden + bias[lane];
            if (ACT) o = o > 0.f ? o : expm1f(o);
            if constexpr (POOL) {
                int g = batch[d];
                atomicAdd(&outf[(size_t)g * 64 + lane], o);
                if (lane == 0) atomicAdd(&gcnt[g], 1);
            } else {
                unsigned short hb, lb;
                splitbf(o, hb, lb);
                out_hi[(size_t)d * TOT + lane] = hb;
                out_lo[(size_t)d * TOT + lane] = lb;
            }
        }
        return;
    }

    // ---- fallback: deg > CAP, serial 3-pass (no LDS) ----
    {
        float adh = ad[head];
        float es = e_self[head];
        float m = es;
        for (int e = p0; e < p1; ++e) {
            int s = csr_src[e];
            m = fmaxf(m, lrelu(al_s[(size_t)s * H + head] + adh));
        }
        float den = __expf(es - m);
        for (int e = p0; e < p1; ++e) {
            int s = csr_src[e];
            den += __expf(lrelu(al_s[(size_t)s * H + head] + adh) - m);
        }
        den = 1.f / den;
        float accv[VEC] = {};
        {
            float alpha = __expf(es - m) * den;
            const unsigned short* hp = hlin + (size_t)d * TOT + lane * VEC;
            #pragma unroll
            for (int v = 0; v < VEC; ++v) accv[v] = alpha * bf2f(hp[v]);
        }
        for (int e = p0; e < p1; ++e) {
            int s = csr_src[e];
            float alpha = __expf(lrelu(al_s[(size_t)s * H + head] + adh) - m) * den;
            const unsigned short* hp = hlin + (size_t)s * TOT + lane * VEC;
            #pragma unroll
            for (int v = 0; v < VEC; ++v) accv[v] += alpha * bf2f(hp[v]);
        }
        #pragma unroll
        for (int v = 0; v < VEC; ++v) {
            int c = lane * VEC + v;
            float o = accv[v] + bias[c];
            if (ACT) o = o > 0.f ? o : expm1f(o);
            accv[v] = o;
        }
        if constexpr (POOL) {
            int g = batch[d];
            atomicAdd(&outf[(size_t)g * 64 + lane], accv[0]);
            if (lane == 0) atomicAdd(&gcnt[g], 1);
        } else {
            #pragma unroll
            for (int v = 0; v < VEC; ++v) {
                unsigned short hb, lb;
                splitbf(accv[v], hb, lb);
                out_hi[(size_t)d * TOT + lane * VEC + v] = hb;
                out_lo[(size_t)d * TOT + lane * VEC + v] = lb;
            }
        }
    }
}

// ---------------- final linear ----------------
__global__ void k_final(const float* __restrict__ gsum, const int* __restrict__ gcnt,
                        const float* __restrict__ lin_w, const float* __restrict__ lin_b,
                        float* __restrict__ out, int Gn) {
    int g = (blockIdx.x * blockDim.x + threadIdx.x) >> 6;
    int lane = threadIdx.x & 63;
    if (g >= Gn) return;
    float cnt = (float)gcnt[g];
    float inv = 1.f / fmaxf(cnt, 1.f);
    float v = gsum[(size_t)g * 64 + lane] * inv * lin_w[lane];
    #pragma unroll
    for (int off = 32; off >= 1; off >>= 1) v += __shfl_xor(v, off);
    if (lane == 0) out[g] = v + lin_b[0];
}

extern "C" void kernel_launch(void* const* d_in, const int* in_sizes, int n_in,
                              void* d_out, int out_size, void* d_ws, size_t ws_size,
                              hipStream_t stream) {
    const float* x    = (const float*)d_in[0];
    const int*   ei   = (const int*)d_in[1];
    const int*   batch= (const int*)d_in[2];
    const float* W1   = (const float*)d_in[3];
    const float* a1s  = (const float*)d_in[4];
    const float* a1d  = (const float*)d_in[5];
    const float* b1   = (const float*)d_in[6];
    const float* W2   = (const float*)d_in[7];
    const float* a2s  = (const float*)d_in[8];
    const float* a2d  = (const float*)d_in[9];
    const float* b2   = (const float*)d_in[10];
    const float* W3   = (const float*)d_in[11];
    const float* a3s  = (const float*)d_in[12];
    const float* a3d  = (const float*)d_in[13];
    const float* b3   = (const float*)d_in[14];
    const float* lw   = (const float*)d_in[15];
    const float* lb   = (const float*)d_in[16];

    int N = in_sizes[0] / 128;
    int E = in_sizes[1] / 2;
    int G = out_size;
    int RT32 = (N + 31) >> 5;      // 32-row tiles (layers 1-2)
    int RT64 = (N + 63) >> 6;      // 64-row tiles (layer 3)
    int Np = ((N + 127) >> 7) * 128;
    int NB = (N + 1023) >> 10;     // scan blocks (<=64 supported)

    char* p = (char*)d_ws;
    auto alloc = [&](size_t bytes) {
        char* r = p;
        p += (bytes + 255) & ~(size_t)255;
        return r;
    };
    unsigned short* hbuf = (unsigned short*)alloc((size_t)Np * 256 * 2);  // bf16 GEMM output
    unsigned short* aggh = (unsigned short*)alloc((size_t)Np * 256 * 2);  // agg out hi plane
    unsigned short* aggl = (unsigned short*)alloc((size_t)Np * 256 * 2);  // agg out lo plane
    unsigned short* pB1h = (unsigned short*)alloc((size_t)128 * 256 * 2);
    unsigned short* pB1l = (unsigned short*)alloc((size_t)128 * 256 * 2);
    unsigned short* pB2h = (unsigned short*)alloc((size_t)256 * 256 * 2);
    unsigned short* pB2l = (unsigned short*)alloc((size_t)256 * 256 * 2);
    unsigned short* pB3h = (unsigned short*)alloc((size_t)256 * 64 * 2);
    unsigned short* pB3l = (unsigned short*)alloc((size_t)256 * 64 * 2);
    float* al_s  = (float*)alloc((size_t)N * 4 * 4);
    float* al_d  = (float*)alloc((size_t)N * 4 * 4);
    int* indptr  = (int*)alloc((size_t)(N + 1) * 4);
    int* counts  = (int*)alloc((size_t)N * 4);
    int* cursor  = (int*)alloc((size_t)N * 4);
    int* lex     = (int*)alloc((size_t)N * 4);
    int* bsums   = (int*)alloc((size_t)256 * 4);
    int* csr     = (int*)alloc((size_t)E * 4);
    float* gsum  = (float*)alloc((size_t)G * 64 * 4);
    int* gcnt    = (int*)alloc((size_t)G * 4);
    if ((size_t)(p - (char*)d_ws) > ws_size) return;  // workspace too small

    hipMemsetAsync(counts, 0, (size_t)N * 4, stream);
    hipMemsetAsync(gsum, 0, (size_t)G * 64 * 4, stream);
    hipMemsetAsync(gcnt, 0, (size_t)G * 4, stream);

    k_packB3<<<(14336 + 255) / 256, 256, 0, stream>>>(W1, W2, W3,
        pB1h, pB1l, pB2h, pB2l, pB3h, pB3l);

    int eb = (E + 255) / 256;
    k_count<<<eb, 256, 0, stream>>>(ei, E, counts);
    k_scan_local<<<NB, 256, 0, stream>>>(counts, lex, bsums, N);
    k_scan_add<<<(N + 1 + 255) / 256, 256, 0, stream>>>(lex, bsums, indptr, cursor, N, E, NB);
    k_scatter<<<eb, 256, 0, stream>>>(ei, E, cursor, csr);

    int wb = (N * 64 + 255) / 256;   // one wave per node

    // layer 1: 128 -> 256 (H=4, concat, ELU); A = x f32 (CONV); 32-row blocks
    k_mm<2, 1, 4, true, 128><<<dim3(RT32, 1), 256, 0, stream>>>(x, nullptr, nullptr,
        pB1h, pB1l, hbuf, a1s, a1d, al_s, al_d, N, 256);
    k_agg<4, true, false><<<wb, 256, 0, stream>>>(hbuf, al_s, al_d, indptr, csr, b1,
        aggh, aggl, nullptr, nullptr, nullptr, N);

    // layer 2: 256 -> 256 (H=4, concat, ELU); A pre-split; 32-row blocks
    k_mm<2, 1, 4, false, 256><<<dim3(RT32, 1), 256, 0, stream>>>(nullptr, aggh, aggl,
        pB2h, pB2l, hbuf, a2s, a2d, al_s, al_d, N, 256);
    k_agg<4, true, false><<<wb, 256, 0, stream>>>(hbuf, al_s, al_d, indptr, csr, b2,
        aggh, aggl, nullptr, nullptr, nullptr, N);

    // layer 3: 256 -> 64 (H=1) + fused mean-pool; 64-row blocks
    k_mm<1, 4, 1, false, 256><<<dim3(RT64, 1), 256, 0, stream>>>(nullptr, aggh, aggl,
        pB3h, pB3l, hbuf, a3s, a3d, al_s, al_d, N, 64);
    k_agg<1, false, true><<<wb, 256, 0, stream>>>(hbuf, al_s, al_d, indptr, csr, b3,
        nullptr, nullptr, gsum, batch, gcnt, N);

    int fb = (G * 64 + 255) / 256;
    k_final<<<fb, 256, 0, stream>>>(gsum, gcnt, lw, lb, (float*)d_out, G);
}